// Round 1
// baseline (164489.111 us; speedup 1.0000x reference)
//
#include <hip/hip_runtime.h>
#include <hip/hip_bf16.h>
#include <math.h>

#define NLAYERS 32
#define DM 1440
#define DI 2880
#define DSTATE 128
#define HD 64
#define NH 45
#define VOCABSZ 256
#define CHUNK 128
#define DXBC 3136
#define DPROJ 6061
#define BB 2
#define LL 2048
#define ROWS (BB*LL)
#define NCH (LL/CHUNK)

__device__ __forceinline__ float sigmoidf_(float x){ return 1.0f/(1.0f+expf(-x)); }

// ---------------- embedding lookup ----------------
__global__ void k_embed(const int* __restrict__ tok, const float* __restrict__ emb, float* __restrict__ h){
  int idx = blockIdx.x*256 + threadIdx.x;
  if (idx >= ROWS*DM) return;
  int row = idx / DM, d = idx - row*DM;
  h[idx] = emb[tok[row]*DM + d];
}

// ---------------- fp32 tiled GEMM: C[M,N] = A[M,K] @ B[K,N] (+C if ACC) ----------------
// M multiple of 128, K multiple of 16 required. N arbitrary (masked).
template<bool ACC>
__global__ __launch_bounds__(256) void k_gemm(const float* __restrict__ A, const float* __restrict__ B,
                                              float* __restrict__ C, int M, int N, int K){
  __shared__ float sA[16][129];
  __shared__ float sB[16][128];
  int tid = threadIdx.x;
  int tx = tid & 15, ty = tid >> 4;
  int m0 = blockIdx.y * 128, n0 = blockIdx.x * 128;
  float acc[8][8];
  #pragma unroll
  for (int i=0;i<8;i++){
    #pragma unroll
    for (int j=0;j<8;j++) acc[i][j]=0.f;
  }
  int nkt = K >> 4;
  for (int kt=0; kt<nkt; ++kt){
    int k0 = kt<<4;
    #pragma unroll
    for (int i=0;i<8;i++){
      int e = tid + i*256;
      int m = e >> 4, kk = e & 15;
      sA[kk][m] = A[(size_t)(m0+m)*K + k0 + kk];
    }
    #pragma unroll
    for (int i=0;i<8;i++){
      int e = tid + i*256;
      int kk = e >> 7, n = e & 127;
      int col = n0 + n;
      sB[kk][n] = (col < N) ? B[(size_t)(k0+kk)*N + col] : 0.f;
    }
    __syncthreads();
    #pragma unroll
    for (int kk=0;kk<16;kk++){
      float a[8], b[8];
      #pragma unroll
      for (int i=0;i<8;i++) a[i] = sA[kk][ty + i*16];
      #pragma unroll
      for (int j=0;j<8;j++) b[j] = sB[kk][tx + j*16];
      #pragma unroll
      for (int i=0;i<8;i++){
        #pragma unroll
        for (int j=0;j<8;j++) acc[i][j] += a[i]*b[j];
      }
    }
    __syncthreads();
  }
  #pragma unroll
  for (int i=0;i<8;i++){
    int row = m0 + ty + i*16;
    if (row < M){
      #pragma unroll
      for (int j=0;j<8;j++){
        int col = n0 + tx + j*16;
        if (col < N){
          size_t off = (size_t)row*N + col;
          C[off] = acc[i][j] + (ACC ? C[off] : 0.f);
        }
      }
    }
  }
}

// ---------------- causal depthwise conv(4) + SiLU ----------------
__global__ void k_conv(const float* __restrict__ zx, const float* __restrict__ cw,
                       const float* __restrict__ cb, float* __restrict__ xbc){
  int ch = blockIdx.x*256 + threadIdx.x;
  if (ch >= DXBC) return;
  int l = blockIdx.y, b = blockIdx.z;
  int row = b*LL + l;
  float s = cb[ch];
  #pragma unroll
  for (int k=0;k<4;k++){
    int t = l - 3 + k;
    if (t >= 0) s += cw[ch*4+k] * zx[(size_t)(b*LL+t)*DPROJ + DI + ch];
  }
  xbc[(size_t)row*DXBC + ch] = s * sigmoidf_(s);
}

// ---------------- dt = softplus(raw + bias) ----------------
__global__ void k_dt(const float* __restrict__ zx, const float* __restrict__ dtb_in, float* __restrict__ dt){
  int idx = blockIdx.x*256+threadIdx.x;
  if (idx >= ROWS*NH) return;
  int row = idx / NH, hh = idx - row*NH;
  float v = zx[(size_t)row*DPROJ + (DPROJ-NH) + hh] + dtb_in[hh];
  dt[idx] = (v > 20.f) ? v : log1pf(expf(v));
}

// ---------------- per-chunk SSD: cumsum(A), Y_diag, chunk states ----------------
__global__ __launch_bounds__(256) void k_ssd_chunk(const float* __restrict__ xbc, const float* __restrict__ dt,
                            const float* __restrict__ A_log_l, float* __restrict__ acs,
                            float* __restrict__ Y, float* __restrict__ cst){
  __shared__ float sB[CHUNK*DSTATE];   // 64 KB
  __shared__ float sX[CHUNK*HD];       // 32 KB
  __shared__ float sAcs[CHUNK];
  int tid = threadIdx.x;
  int hh = blockIdx.x, c = blockIdx.y, b = blockIdx.z;
  int t0 = b*LL + c*CHUNK;
  float A_h = -expf(A_log_l[hh]);
  if (tid < CHUNK) sAcs[tid] = dt[(size_t)(t0+tid)*NH + hh] * A_h;
  #pragma unroll 8
  for (int i=0;i<64;i++){
    int e = tid + i*256;
    int l = e >> 7, n = e & 127;
    sB[e] = xbc[(size_t)(t0+l)*DXBC + DI + n];
  }
  #pragma unroll 8
  for (int i=0;i<32;i++){
    int e = tid + i*256;
    int l = e >> 6, p = e & 63;
    sX[e] = xbc[(size_t)(t0+l)*DXBC + hh*HD + p] * dt[(size_t)(t0+l)*NH + hh];
  }
  __syncthreads();
  if (tid == 0){
    float csum = 0.f;
    for (int t=0;t<CHUNK;t++){ csum += sAcs[t]; sAcs[t] = csum; }
  }
  __syncthreads();
  if (tid < CHUNK) acs[(size_t)(t0+tid)*NH + hh] = sAcs[tid];

  // Y_diag: thread owns row l = tid>>1, half of p-dim
  int l = tid >> 1, pp = (tid & 1) * 32;
  const float* Crow = xbc + (size_t)(t0+l)*DXBC + DI + DSTATE;
  float al = sAcs[l];
  float acc[32];
  #pragma unroll
  for (int p=0;p<32;p++) acc[p]=0.f;
  for (int s=0;s<=l;s++){
    float dot = 0.f;
    const float* Bs = sB + s*DSTATE;
    #pragma unroll 4
    for (int n=0;n<DSTATE;n++) dot += Crow[n]*Bs[n];
    float w = dot * expf(al - sAcs[s]);
    const float* xs = sX + s*HD + pp;
    #pragma unroll
    for (int p=0;p<32;p++) acc[p] += w * xs[p];
  }
  {
    float* yp = Y + (size_t)(t0+l)*DI + hh*HD + pp;
    #pragma unroll
    for (int p=0;p<32;p++) yp[p] = acc[p];
  }
  __syncthreads();
  // scale X in place by decay-to-chunk-end
  float alast = sAcs[CHUNK-1];
  #pragma unroll 8
  for (int i=0;i<32;i++){
    int e = tid + i*256;
    int lr = e >> 6;
    sX[e] *= expf(alast - sAcs[lr]);
  }
  __syncthreads();
  // chunk state[n,p] = sum_l B[l,n] * decayedX[l,p]
  int n = tid >> 1;
  float st[32];
  #pragma unroll
  for (int p=0;p<32;p++) st[p]=0.f;
  for (int lr=0; lr<CHUNK; ++lr){
    float bv = sB[lr*DSTATE + n];
    const float* xs = sX + lr*HD + pp;
    #pragma unroll
    for (int p=0;p<32;p++) st[p] += bv * xs[p];
  }
  {
    float* cp = cst + ((size_t)(b*NCH + c)*NH + hh)*(DSTATE*HD) + n*HD + pp;
    #pragma unroll
    for (int p=0;p<32;p++) cp[p] = st[p];
  }
}

// ---------------- sequential inter-chunk scan + Y_off ----------------
__global__ __launch_bounds__(256) void k_ssd_scan(const float* __restrict__ xbc, const float* __restrict__ acs,
                           const float* __restrict__ cst, float* __restrict__ Y){
  __shared__ float sS[DSTATE*HD]; // 32 KB
  int tid = threadIdx.x;
  int hh = blockIdx.x, b = blockIdx.y;
  #pragma unroll 8
  for (int i=0;i<32;i++) sS[tid + i*256] = 0.f;
  int l = tid >> 1, pp = (tid & 1)*32;
  for (int c=0;c<NCH;c++){
    int t0 = b*LL + c*CHUNK;
    __syncthreads();
    float acc[32];
    #pragma unroll
    for (int p=0;p<32;p++) acc[p]=0.f;
    const float* Crow = xbc + (size_t)(t0+l)*DXBC + DI + DSTATE;
    for (int n=0;n<DSTATE;n++){
      float cv = Crow[n];
      const float* xs = sS + n*HD + pp;
      #pragma unroll
      for (int p=0;p<32;p++) acc[p] += cv * xs[p];
    }
    float ea = expf(acs[(size_t)(t0+l)*NH + hh]);
    float* yp = Y + (size_t)(t0+l)*DI + hh*HD + pp;
    #pragma unroll
    for (int p=0;p<32;p++) yp[p] += ea * acc[p];
    float dec = expf(acs[(size_t)(t0+CHUNK-1)*NH + hh]);
    __syncthreads();
    const float* cp = cst + ((size_t)(b*NCH + c)*NH + hh)*(DSTATE*HD);
    #pragma unroll 8
    for (int i=0;i<32;i++){
      int e = tid + i*256;
      sS[e] = dec * sS[e] + cp[e];
    }
  }
}

// ---------------- y = (Y + x*Dp) * silu(z); RMSNorm * norm_w ----------------
__global__ __launch_bounds__(256) void k_gatenorm(float* __restrict__ Y, const float* __restrict__ xbc,
                           const float* __restrict__ zx, const float* __restrict__ Dp_l,
                           const float* __restrict__ nw){
  __shared__ float red[4];
  __shared__ float stot;
  int row = blockIdx.x;
  int tid = threadIdx.x;
  float ss = 0.f;
  for (int d = tid; d < DI; d += 256){
    float xv = xbc[(size_t)row*DXBC + d];
    float yv = Y[(size_t)row*DI + d] + xv * Dp_l[d >> 6];
    float zv = zx[(size_t)row*DPROJ + d];
    yv *= zv * sigmoidf_(zv);
    Y[(size_t)row*DI + d] = yv;
    ss += yv*yv;
  }
  #pragma unroll
  for (int off=32; off>0; off>>=1) ss += __shfl_down(ss, off, 64);
  int lane = tid & 63, wid = tid >> 6;
  if (lane == 0) red[wid] = ss;
  __syncthreads();
  if (tid == 0) stot = red[0]+red[1]+red[2]+red[3];
  __syncthreads();
  float rs = rsqrtf(stot / (float)DI + 1e-5f);
  for (int d = tid; d < DI; d += 256){
    Y[(size_t)row*DI + d] *= rs * nw[d];
  }
}

// ---------------- final RMSNorm ----------------
__global__ __launch_bounds__(256) void k_finalnorm(const float* __restrict__ h, const float* __restrict__ fnw,
                            float* __restrict__ hn){
  __shared__ float red[4];
  __shared__ float stot;
  int row = blockIdx.x;
  int tid = threadIdx.x;
  float ss = 0.f;
  for (int d = tid; d < DM; d += 256){
    float v = h[(size_t)row*DM + d];
    ss += v*v;
  }
  #pragma unroll
  for (int off=32; off>0; off>>=1) ss += __shfl_down(ss, off, 64);
  int lane = tid & 63, wid = tid >> 6;
  if (lane == 0) red[wid] = ss;
  __syncthreads();
  if (tid == 0) stot = red[0]+red[1]+red[2]+red[3];
  __syncthreads();
  float rs = rsqrtf(stot / (float)DM + 1e-5f);
  for (int d = tid; d < DM; d += 256){
    hn[(size_t)row*DM + d] = h[(size_t)row*DM + d] * rs * fnw[d];
  }
}

// ---------------- embed transpose (for logits GEMM B operand) ----------------
__global__ void k_transp(const float* __restrict__ emb, float* __restrict__ embT){
  int idx = blockIdx.x*256+threadIdx.x;
  if (idx >= DM*VOCABSZ) return;
  int k = idx >> 8, n = idx & 255;
  embT[idx] = emb[n*DM + k];
}

extern "C" void kernel_launch(void* const* d_in, const int* in_sizes, int n_in,
                              void* d_out, int out_size, void* d_ws, size_t ws_size,
                              hipStream_t stream){
  const int*   tok   = (const int*)d_in[0];
  const float* emb   = (const float*)d_in[1];
  const float* Win   = (const float*)d_in[2];
  const float* convw = (const float*)d_in[3];
  const float* convb = (const float*)d_in[4];
  const float* dtbias= (const float*)d_in[5];
  const float* Alog  = (const float*)d_in[6];
  const float* Dp    = (const float*)d_in[7];
  const float* normw = (const float*)d_in[8];
  const float* Wout  = (const float*)d_in[9];
  const float* fnw   = (const float*)d_in[10];

  float* ws = (float*)d_ws;
  float* h    = ws;                 // 4096*1440  = 5,898,240
  float* zx   = ws + 5898240;       // 4096*6061  = 24,825,856
  float* xbc  = ws + 30724096;      // 4096*3136  = 12,845,056
  float* dtb  = ws + 43569152;      // 4096*45    = 184,320
  float* acs  = ws + 43753472;      // 4096*45    = 184,320
  float* Yb   = ws + 43937792;      // 4096*2880  = 11,796,480 (also reused as hn)
  float* cst  = ws + 55734272;      // 2*16*45*128*64 = 11,796,480
  float* embT = ws + 67530752;      // 1440*256   = 368,640

  k_embed<<<(ROWS*DM+255)/256, 256, 0, stream>>>(tok, emb, h);
  for (int lyr=0; lyr<NLAYERS; ++lyr){
    k_gemm<false><<<dim3((DPROJ+127)/128, ROWS/128), 256, 0, stream>>>(
        h, Win + (size_t)lyr*DM*DPROJ, zx, ROWS, DPROJ, DM);
    k_conv<<<dim3((DXBC+255)/256, LL, BB), 256, 0, stream>>>(
        zx, convw + (size_t)lyr*DXBC*4, convb + (size_t)lyr*DXBC, xbc);
    k_dt<<<(ROWS*NH+255)/256, 256, 0, stream>>>(zx, dtbias + lyr*NH, dtb);
    k_ssd_chunk<<<dim3(NH, NCH, BB), 256, 0, stream>>>(xbc, dtb, Alog + lyr*NH, acs, Yb, cst);
    k_ssd_scan<<<dim3(NH, BB), 256, 0, stream>>>(xbc, acs, cst, Yb);
    k_gatenorm<<<ROWS, 256, 0, stream>>>(Yb, xbc, zx, Dp + lyr*NH, normw + (size_t)lyr*DI);
    k_gemm<true><<<dim3((DM+127)/128, ROWS/128), 256, 0, stream>>>(
        Yb, Wout + (size_t)lyr*DI*DM, h, ROWS, DM, DI);
  }
  k_finalnorm<<<ROWS, 256, 0, stream>>>(h, fnw, Yb);
  k_transp<<<(DM*VOCABSZ+255)/256, 256, 0, stream>>>(emb, embT);
  k_gemm<false><<<dim3(VOCABSZ/128, ROWS/128), 256, 0, stream>>>(
      Yb, embT, (float*)d_out, ROWS, VOCABSZ, DM);
}

// Round 4
// 27908.353 us; speedup vs baseline: 5.8939x; 5.8939x over previous
//
#include <hip/hip_runtime.h>
#include <hip/hip_bf16.h>
#include <math.h>

#define NLAYERS 32
#define DM 1440
#define DI 2880
#define DSTATE 128
#define HD 64
#define NH 45
#define VOCABSZ 256
#define CHUNK 128
#define DXBC 3136
#define DPROJ 6061
#define BB 2
#define LL 2048
#define ROWS (BB*LL)
#define NCH (LL/CHUNK)
#define ZXS 6144          // padded zx row stride
#define STR 136           // LDS leading dim for [*][128] tiles (2-way bank alias: free)
#define STR2 68           // LDS leading dim for [*][64] tiles

typedef __attribute__((ext_vector_type(8))) short bf16x8;
typedef __attribute__((ext_vector_type(4))) float f32x4;
typedef unsigned short us;

__device__ __forceinline__ float sigmoidf_(float x){ return 1.0f/(1.0f+__expf(-x)); }
__device__ __forceinline__ us f2b(float f){
  unsigned int u = __float_as_uint(f);
  return (us)((u + 0x7FFFu + ((u>>16)&1u)) >> 16);
}
__device__ __forceinline__ float b2f(us s){
  return __uint_as_float(((unsigned int)s)<<16);
}
__device__ __forceinline__ void split2(float v, us* ph, us* pl){
  us h = f2b(v);
  *ph = h;
  *pl = f2b(v - b2f(h));
}
__device__ __forceinline__ void gl2lds16(const us* g, us* l){
  __builtin_amdgcn_global_load_lds((const __attribute__((address_space(1))) unsigned int*)g,
                                   (__attribute__((address_space(3))) unsigned int*)l, 16, 0, 0);
}
#define MFMA(a,b,c) __builtin_amdgcn_mfma_f32_16x16x32_bf16(a,b,c,0,0,0)

// ---------------- embedding lookup (h tight [4096][1440]) ----------------
__global__ void k_embed(const int* __restrict__ tok, const float* __restrict__ emb, float* __restrict__ h){
  int idx = blockIdx.x*256 + threadIdx.x;
  if (idx >= ROWS*DM) return;
  int row = idx / DM, d = idx - row*DM;
  h[idx] = emb[tok[row]*DM + d];
}

// ---------------- split fp32 rows (tight) -> hi/lo bf16 (tight) ----------------
__global__ void k_split_rows(const float* __restrict__ src, us* __restrict__ dh,
                             us* __restrict__ dl, int ncols){
  size_t e = ((size_t)blockIdx.x*256 + threadIdx.x)*8;
  const float* s = src + e;
  bf16x8 oh, ol;
  #pragma unroll
  for (int j=0;j<8;j++){
    float v = s[j];
    us hh = f2b(v);
    ((us*)&oh)[j] = hh;
    ((us*)&ol)[j] = f2b(v - b2f(hh));
  }
  *(bf16x8*)(dh + e) = oh;
  *(bf16x8*)(dl + e) = ol;
}

// ---------------- W[K][N] fp32 -> WTh/WTl[Npad][K] bf16 (zero pad rows) ----------------
__global__ void k_transcast_sp(const float* __restrict__ W, us* __restrict__ WTh,
                               us* __restrict__ WTl, int K, int N){
  __shared__ float t[32][65];
  int tid = threadIdx.x;
  int n0 = blockIdx.x*64, k0 = blockIdx.y*32;
  #pragma unroll
  for (int i=0;i<8;i++){
    int e = i*256 + tid;
    int r = e >> 6, cc = e & 63;
    int n = n0 + cc;
    t[r][cc] = (n < N) ? W[(size_t)(k0+r)*N + n] : 0.f;
  }
  __syncthreads();
  int nrow = tid >> 2, kseg = (tid & 3)*8;
  bf16x8 oh, ol;
  #pragma unroll
  for (int j=0;j<8;j++){
    float v = t[kseg+j][nrow];
    us hh = f2b(v);
    ((us*)&oh)[j] = hh;
    ((us*)&ol)[j] = f2b(v - b2f(hh));
  }
  *(bf16x8*)(WTh + (size_t)(n0+nrow)*K + k0 + kseg) = oh;
  *(bf16x8*)(WTl + (size_t)(n0+nrow)*K + k0 + kseg) = ol;
}

// ---------------- split-bf16 MFMA GEMM: C[M,ntiles*128] (+)= (Ah+Al) @ (Bh+Bl)^T ----------------
// A tight [4096][K] split pair; BT [Npad][K] split pair; C fp32 ldc stride, cols masked to < N.
template<bool ACC>
__global__ __launch_bounds__(256) void k_gemm_sp(const us* __restrict__ Ah, const us* __restrict__ Al,
      const us* __restrict__ Bh, const us* __restrict__ Bl, float* __restrict__ C,
      int K, int ldc, int N, int nbx){
  __shared__ __align__(16) us sAh[4096], sAl[4096], sBh[4096], sBl[4096];
  int nwg = gridDim.x;
  int q = nwg >> 3;
  int bid = blockIdx.x;
  int wg = (bid & 7)*q + (bid >> 3);     // XCD swizzle (nwg % 8 == 0 for all our grids)
  int bx = wg % nbx, by = wg / nbx;
  int m0 = by*128, n0 = bx*128;
  int tid = threadIdx.x;
  int lane = tid & 63, wid = tid >> 6;
  int wr = wid >> 1, wc = wid & 1;
  int r4 = lane >> 2, c4 = (lane & 3)*8;
  int fr = lane & 15, fk = (lane >> 4)*8;
  f32x4 acc[4][4];
  #pragma unroll
  for (int i=0;i<4;i++)
    #pragma unroll
    for (int j=0;j<4;j++) acc[i][j] = (f32x4){0.f,0.f,0.f,0.f};
  for (int kt = 0; kt < K; kt += 32){
    __syncthreads();
    size_t ra0 = (size_t)(m0 + wid*16     + r4)*K + kt + c4;
    size_t ra1 = (size_t)(m0 + (wid+4)*16 + r4)*K + kt + c4;
    size_t rb0 = (size_t)(n0 + wid*16     + r4)*K + kt + c4;
    size_t rb1 = (size_t)(n0 + (wid+4)*16 + r4)*K + kt + c4;
    gl2lds16(Ah + ra0, sAh + wid*512);
    gl2lds16(Ah + ra1, sAh + (wid+4)*512);
    gl2lds16(Al + ra0, sAl + wid*512);
    gl2lds16(Al + ra1, sAl + (wid+4)*512);
    gl2lds16(Bh + rb0, sBh + wid*512);
    gl2lds16(Bh + rb1, sBh + (wid+4)*512);
    gl2lds16(Bl + rb0, sBl + wid*512);
    gl2lds16(Bl + rb1, sBl + (wid+4)*512);
    __syncthreads();
    bf16x8 ah[4], al[4], bh[4], bl[4];
    #pragma unroll
    for (int i=0;i<4;i++){
      int ro = (wr*64 + i*16 + fr)*32 + fk;
      int co = (wc*64 + i*16 + fr)*32 + fk;
      ah[i] = *(const bf16x8*)(sAh + ro);
      al[i] = *(const bf16x8*)(sAl + ro);
      bh[i] = *(const bf16x8*)(sBh + co);
      bl[i] = *(const bf16x8*)(sBl + co);
    }
    #pragma unroll
    for (int i=0;i<4;i++)
      #pragma unroll
      for (int j=0;j<4;j++){
        acc[i][j] = MFMA(ah[i], bh[j], acc[i][j]);
        acc[i][j] = MFMA(ah[i], bl[j], acc[i][j]);
        acc[i][j] = MFMA(al[i], bh[j], acc[i][j]);
      }
  }
  int orow = (lane>>4)*4, ocol = lane & 15;
  #pragma unroll
  for (int i=0;i<4;i++)
    #pragma unroll
    for (int j=0;j<4;j++)
      #pragma unroll
      for (int r=0;r<4;r++){
        int col = n0 + wc*64 + j*16 + ocol;
        if (col < N){
          size_t off = (size_t)(m0 + wr*64 + i*16 + orow + r)*ldc + col;
          C[off] = acc[i][j][r] + (ACC ? C[off] : 0.f);
        }
      }
}

// ---------------- causal depthwise conv(4) + SiLU ----------------
__global__ void k_conv(const float* __restrict__ zx, const float* __restrict__ cw,
                       const float* __restrict__ cb, float* __restrict__ xbc){
  int ch = blockIdx.x*256 + threadIdx.x;
  if (ch >= DXBC) return;
  int l = blockIdx.y, b = blockIdx.z;
  int row = b*LL + l;
  float s = cb[ch];
  #pragma unroll
  for (int k=0;k<4;k++){
    int t = l - 3 + k;
    if (t >= 0) s += cw[ch*4+k] * zx[(size_t)(b*LL+t)*ZXS + DI + ch];
  }
  xbc[(size_t)row*DXBC + ch] = s * sigmoidf_(s);
}

// ---------------- dt = softplus(raw + bias) ----------------
__global__ void k_dt(const float* __restrict__ zx, const float* __restrict__ dtb_in, float* __restrict__ dt){
  int idx = blockIdx.x*256+threadIdx.x;
  if (idx >= ROWS*NH) return;
  int row = idx / NH, hh = idx - row*NH;
  float v = zx[(size_t)row*ZXS + (DI+DXBC) + hh] + dtb_in[hh];
  dt[idx] = (v > 20.f) ? v : log1pf(expf(v));
}

// ---------------- SSD A: acs cumsum + chunk states via split-MFMA; cst[p][n] fp32 ----------------
__global__ __launch_bounds__(256) void k_ssd_state_sp(const float* __restrict__ xbc,
    const float* __restrict__ dtb, const float* __restrict__ Alog,
    float* __restrict__ acs, float* __restrict__ cst){
  __shared__ __align__(16) us sBTh[128*STR];   // [n][l]
  __shared__ __align__(16) us sBTl[128*STR];
  __shared__ __align__(16) us sXTh[64*STR];    // [p][l]
  __shared__ __align__(16) us sXTl[64*STR];
  __shared__ float sAcs[128];
  __shared__ float sDt[128];
  int tid = threadIdx.x;
  int hh = blockIdx.x, c = blockIdx.y, b = blockIdx.z;
  int t0 = b*LL + c*CHUNK;
  float A_h = -__expf(Alog[hh]);
  if (tid < 128){
    float d = dtb[(size_t)(t0+tid)*NH + hh];
    sDt[tid] = d;
    sAcs[tid] = d * A_h;
  }
  __syncthreads();
  if (tid < 64){
    float v = sAcs[tid], w = sAcs[64+tid];
    #pragma unroll
    for (int off=1; off<64; off<<=1){
      float tv = __shfl_up(v, off, 64);
      float tw = __shfl_up(w, off, 64);
      if (tid >= off){ v += tv; w += tw; }
    }
    float tot = __shfl(v, 63, 64);
    sAcs[tid] = v;
    sAcs[64+tid] = w + tot;
  }
  __syncthreads();
  if (tid < 128) acs[(size_t)(t0+tid)*NH + hh] = sAcs[tid];
  float alast = sAcs[127];
  #pragma unroll 8
  for (int i=0;i<64;i++){
    int e = i*256 + tid;
    int l = e >> 7, n = e & 127;
    split2(xbc[(size_t)(t0+l)*DXBC + DI + n], &sBTh[n*STR+l], &sBTl[n*STR+l]);
  }
  #pragma unroll 8
  for (int i=0;i<32;i++){
    int e = i*256 + tid;
    int l = e >> 6, p = e & 63;
    float v = xbc[(size_t)(t0+l)*DXBC + hh*HD + p] * sDt[l] * __expf(alast - sAcs[l]);
    split2(v, &sXTh[p*STR+l], &sXTl[p*STR+l]);
  }
  __syncthreads();
  int lane = tid & 63, wid = tid >> 6;
  int fr = lane & 15, fk = (lane>>4)*8;
  f32x4 acc[8];
  #pragma unroll
  for (int j=0;j<8;j++) acc[j] = (f32x4){0.f,0.f,0.f,0.f};
  #pragma unroll
  for (int ks=0; ks<4; ks++){
    bf16x8 ah = *(const bf16x8*)(sXTh + (wid*16 + fr)*STR + ks*32 + fk);
    bf16x8 al = *(const bf16x8*)(sXTl + (wid*16 + fr)*STR + ks*32 + fk);
    #pragma unroll
    for (int j=0;j<8;j++){
      bf16x8 bh = *(const bf16x8*)(sBTh + (j*16 + fr)*STR + ks*32 + fk);
      bf16x8 bl = *(const bf16x8*)(sBTl + (j*16 + fr)*STR + ks*32 + fk);
      acc[j] = MFMA(ah, bh, acc[j]);
      acc[j] = MFMA(ah, bl, acc[j]);
      acc[j] = MFMA(al, bh, acc[j]);
    }
  }
  size_t cbase = (((size_t)(b*NCH + c)*NH) + hh)*8192;
  int orow = (lane>>4)*4;
  #pragma unroll
  for (int j=0;j<8;j++)
    #pragma unroll
    for (int r=0;r<4;r++){
      int p = wid*16 + orow + r;
      int n = j*16 + fr;
      cst[cbase + p*128 + n] = acc[j][r];
    }
}

// ---------------- SSD B: sequential inter-chunk prefix (fp32, in place, elementwise) ----------------
__global__ __launch_bounds__(256) void k_ssd_scan2(const float* __restrict__ acs,
      float* __restrict__ cst){
  int tid = threadIdx.x;
  int hh = blockIdx.x, b = blockIdx.y, z = blockIdx.z;
  int base_e = z*1024;
  float P[4];
  #pragma unroll
  for (int i=0;i<4;i++) P[i] = 0.f;
  for (int c=0;c<NCH;c++){
    size_t base = (((size_t)(b*NCH + c)*NH) + hh)*8192 + base_e;
    float dec = __expf(acs[(size_t)(b*LL + c*CHUNK + CHUNK-1)*NH + hh]);
    #pragma unroll
    for (int i=0;i<4;i++){
      int e = i*256 + tid;
      float tmp = cst[base + e];
      cst[base + e] = P[i];
      P[i] = dec*P[i] + tmp;
    }
  }
}

// ---------------- SSD C: Y = (exp-masked C@B^T)@X + exp(acs)*(C@P^T), split-MFMA ----------------
__global__ __launch_bounds__(256) void k_ssd_y_sp(const float* __restrict__ xbc,
    const float* __restrict__ dtb, const float* __restrict__ acs,
    const float* __restrict__ cst, float* __restrict__ Yf){
  __shared__ __align__(16) us smem[52224];
  __shared__ float sAcs[128];
  __shared__ float sDt[128];
  // phase-1 overlay
  us* sCh = smem;          us* sCl = smem + 8704;
  us* sBh = smem + 17408;  us* sBl = smem + 26112;
  us* sPh = smem + 34816;  us* sPl = smem + 39168;
  // phase-2 overlay
  us* sSh = smem;          us* sSl = smem + 17408;
  us* sXh = smem + 34816;  us* sXl = smem + 43520;

  int tid = threadIdx.x;
  int hh = blockIdx.x, c = blockIdx.y, b = blockIdx.z;
  int t0 = b*LL + c*CHUNK;
  if (tid < 128){
    sAcs[tid] = acs[(size_t)(t0+tid)*NH + hh];
    sDt[tid]  = dtb[(size_t)(t0+tid)*NH + hh];
  }
  int lane = tid & 63, wid = tid >> 6;
  int wbase = wid*32;
  int fr = lane & 15, fk = (lane>>4)*8;
  int orow = (lane>>4)*4;
  size_t cbase = (((size_t)(b*NCH + c)*NH) + hh)*8192;

  f32x4 accS[2][8];
  f32x4 accU[2][4];
  #pragma unroll
  for (int m=0;m<2;m++){
    #pragma unroll
    for (int j=0;j<8;j++) accS[m][j] = (f32x4){0.f,0.f,0.f,0.f};
    #pragma unroll
    for (int j=0;j<4;j++) accU[m][j] = (f32x4){0.f,0.f,0.f,0.f};
  }
  #pragma unroll 1
  for (int nt=0; nt<2; ++nt){
    int nb = nt*64;
    __syncthreads();
    #pragma unroll 8
    for (int i=0;i<32;i++){
      int e = i*256 + tid;           // 8192 = 128 l x 64 nn
      int l = e >> 6, nn = e & 63;
      split2(xbc[(size_t)(t0+l)*DXBC + DI + DSTATE + nb + nn], &sCh[l*STR2+nn], &sCl[l*STR2+nn]);
      split2(xbc[(size_t)(t0+l)*DXBC + DI + nb + nn],          &sBh[l*STR2+nn], &sBl[l*STR2+nn]);
    }
    #pragma unroll 8
    for (int i=0;i<16;i++){
      int e = i*256 + tid;           // 4096 = 64 p x 64 nn
      int p = e >> 6, nn = e & 63;
      split2(cst[cbase + p*128 + nb + nn], &sPh[p*STR2+nn], &sPl[p*STR2+nn]);
    }
    __syncthreads();
    #pragma unroll
    for (int ks=0; ks<2; ++ks){
      int ko = ks*32 + fk;
      bf16x8 a0h = *(const bf16x8*)(sCh + (wbase+fr)*STR2 + ko);
      bf16x8 a0l = *(const bf16x8*)(sCl + (wbase+fr)*STR2 + ko);
      bf16x8 a1h = *(const bf16x8*)(sCh + (wbase+16+fr)*STR2 + ko);
      bf16x8 a1l = *(const bf16x8*)(sCl + (wbase+16+fr)*STR2 + ko);
      #pragma unroll
      for (int j=0;j<8;j++){
        bf16x8 bh = *(const bf16x8*)(sBh + (j*16+fr)*STR2 + ko);
        bf16x8 bl = *(const bf16x8*)(sBl + (j*16+fr)*STR2 + ko);
        accS[0][j] = MFMA(a0h, bh, accS[0][j]);
        accS[0][j] = MFMA(a0h, bl, accS[0][j]);
        accS[0][j] = MFMA(a0l, bh, accS[0][j]);
        accS[1][j] = MFMA(a1h, bh, accS[1][j]);
        accS[1][j] = MFMA(a1h, bl, accS[1][j]);
        accS[1][j] = MFMA(a1l, bh, accS[1][j]);
      }
      #pragma unroll
      for (int j=0;j<4;j++){
        bf16x8 ph = *(const bf16x8*)(sPh + (j*16+fr)*STR2 + ko);
        bf16x8 pl = *(const bf16x8*)(sPl + (j*16+fr)*STR2 + ko);
        accU[0][j] = MFMA(a0h, ph, accU[0][j]);
        accU[0][j] = MFMA(a0h, pl, accU[0][j]);
        accU[0][j] = MFMA(a0l, ph, accU[0][j]);
        accU[1][j] = MFMA(a1h, ph, accU[1][j]);
        accU[1][j] = MFMA(a1h, pl, accU[1][j]);
        accU[1][j] = MFMA(a1l, ph, accU[1][j]);
      }
    }
  }
  __syncthreads();
  // S -> masked exp -> split into LDS (overwrites C/B region)
  #pragma unroll
  for (int m=0;m<2;m++)
    #pragma unroll
    for (int j=0;j<8;j++)
      #pragma unroll
      for (int r=0;r<4;r++){
        int l = wbase + m*16 + orow + r;
        int s = j*16 + fr;
        float v = (s <= l) ? accS[m][j][r]*__expf(sAcs[l]-sAcs[s]) : 0.f;
        split2(v, &sSh[l*STR+s], &sSl[l*STR+s]);
      }
  // stage X^T [p][s] (overwrites P region + tail)
  #pragma unroll 8
  for (int i=0;i<32;i++){
    int e = i*256 + tid;             // 8192 = 64 p x 128 s
    int p = e >> 7, s = e & 127;
    float v = xbc[(size_t)(t0+s)*DXBC + hh*HD + p] * sDt[s];
    split2(v, &sXh[p*STR+s], &sXl[p*STR+s]);
  }
  __syncthreads();
  f32x4 accD[2][4];
  #pragma unroll
  for (int m=0;m<2;m++)
    #pragma unroll
    for (int j=0;j<4;j++) accD[m][j] = (f32x4){0.f,0.f,0.f,0.f};
  #pragma unroll
  for (int ks=0; ks<4; ++ks){
    int ko = ks*32 + fk;
    bf16x8 a0h = *(const bf16x8*)(sSh + (wbase+fr)*STR + ko);
    bf16x8 a0l = *(const bf16x8*)(sSl + (wbase+fr)*STR + ko);
    bf16x8 a1h = *(const bf16x8*)(sSh + (wbase+16+fr)*STR + ko);
    bf16x8 a1l = *(const bf16x8*)(sSl + (wbase+16+fr)*STR + ko);
    #pragma unroll
    for (int j=0;j<4;j++){
      bf16x8 xh = *(const bf16x8*)(sXh + (j*16+fr)*STR + ko);
      bf16x8 xl = *(const bf16x8*)(sXl + (j*16+fr)*STR + ko);
      accD[0][j] = MFMA(a0h, xh, accD[0][j]);
      accD[0][j] = MFMA(a0h, xl, accD[0][j]);
      accD[0][j] = MFMA(a0l, xh, accD[0][j]);
      accD[1][j] = MFMA(a1h, xh, accD[1][j]);
      accD[1][j] = MFMA(a1h, xl, accD[1][j]);
      accD[1][j] = MFMA(a1l, xh, accD[1][j]);
    }
  }
  #pragma unroll
  for (int m=0;m<2;m++)
    #pragma unroll
    for (int r=0;r<4;r++){
      int l = wbase + m*16 + orow + r;
      float ea = __expf(sAcs[l]);
      #pragma unroll
      for (int j=0;j<4;j++)
        Yf[(size_t)(t0+l)*DI + hh*HD + j*16 + fr] = accD[m][j][r] + ea*accU[m][j][r];
    }
}

// ---------------- gate + RMSNorm -> split bf16 pair ----------------
__global__ __launch_bounds__(256) void k_gatenorm(const float* __restrict__ Yf,
                           const float* __restrict__ xbc,
                           const float* __restrict__ zx, const float* __restrict__ Dp_l,
                           const float* __restrict__ nw, us* __restrict__ yh, us* __restrict__ yl){
  __shared__ float red[4];
  __shared__ float stot;
  int row = blockIdx.x;
  int tid = threadIdx.x;
  float yv_[12];
  float ss = 0.f;
  #pragma unroll
  for (int i=0;i<12;i++){
    int d = tid + i*256;
    if (d < DI){
      float xv = xbc[(size_t)row*DXBC + d];
      float yv = Yf[(size_t)row*DI + d] + xv * Dp_l[d >> 6];
      float zv = zx[(size_t)row*ZXS + d];
      yv *= zv * sigmoidf_(zv);
      yv_[i] = yv;
      ss += yv*yv;
    } else yv_[i] = 0.f;
  }
  #pragma unroll
  for (int off=32; off>0; off>>=1) ss += __shfl_down(ss, off, 64);
  int lane = tid & 63, wid = tid >> 6;
  if (lane == 0) red[wid] = ss;
  __syncthreads();
  if (tid == 0) stot = red[0]+red[1]+red[2]+red[3];
  __syncthreads();
  float rs = rsqrtf(stot / (float)DI + 1e-5f);
  #pragma unroll
  for (int i=0;i<12;i++){
    int d = tid + i*256;
    if (d < DI){
      float v = yv_[i] * rs * nw[d];
      split2(v, &yh[(size_t)row*DI + d], &yl[(size_t)row*DI + d]);
    }
  }
}

// ---------------- final RMSNorm -> split bf16 pair ----------------
__global__ __launch_bounds__(256) void k_finalnorm(const float* __restrict__ h, const float* __restrict__ fnw,
                            us* __restrict__ oh, us* __restrict__ ol){
  __shared__ float red[4];
  __shared__ float stot;
  int row = blockIdx.x;
  int tid = threadIdx.x;
  float v_[6];
  float ss = 0.f;
  #pragma unroll
  for (int i=0;i<6;i++){
    int d = tid + i*256;
    if (d < DM){ v_[i] = h[(size_t)row*DM + d]; ss += v_[i]*v_[i]; }
    else v_[i] = 0.f;
  }
  #pragma unroll
  for (int off=32; off>0; off>>=1) ss += __shfl_down(ss, off, 64);
  int lane = tid & 63, wid = tid >> 6;
  if (lane == 0) red[wid] = ss;
  __syncthreads();
  if (tid == 0) stot = red[0]+red[1]+red[2]+red[3];
  __syncthreads();
  float rs = rsqrtf(stot / (float)DM + 1e-5f);
  #pragma unroll
  for (int i=0;i<6;i++){
    int d = tid + i*256;
    if (d < DM){
      float v = v_[i] * rs * fnw[d];
      split2(v, &oh[(size_t)row*DM + d], &ol[(size_t)row*DM + d]);
    }
  }
}

extern "C" void kernel_launch(void* const* d_in, const int* in_sizes, int n_in,
                              void* d_out, int out_size, void* d_ws, size_t ws_size,
                              hipStream_t stream){
  const int*   tok   = (const int*)d_in[0];
  const float* emb   = (const float*)d_in[1];
  const float* Win   = (const float*)d_in[2];
  const float* convw = (const float*)d_in[3];
  const float* convb = (const float*)d_in[4];
  const float* dtbias= (const float*)d_in[5];
  const float* Alog  = (const float*)d_in[6];
  const float* Dp    = (const float*)d_in[7];
  const float* normw = (const float*)d_in[8];
  const float* Wout  = (const float*)d_in[9];
  const float* fnw   = (const float*)d_in[10];

  float* ws = (float*)d_ws;
  // layout (floats): total 67,870,720 = 271.48 MB (<= proven 271.59 MB)
  float* h    = ws;                        // [0 .. 5,898,240)       4096x1440 fp32
  float* zx   = ws + 5898240;              // [.. 31,064,064)        4096x6144 fp32
  float* xbc  = ws + 31064064;             // [.. 43,909,120)        4096x3136 fp32
  float* dtb  = ws + 43909120;             // [.. 44,093,440)
  float* acs  = ws + 44093440;             // [.. 44,277,760)
  // region R1 [44,277,760 .. 56,074,240): Yf fp32 (4096x2880)  OVERLAID with wbuf split pair
  float* Yf   = ws + 44277760;
  us* wbuf_h  = (us*)(ws + 44277760);      // up to 6144x1440 bf16 (4,423,680 floats)
  us* wbuf_l  = (us*)(ws + 48701440);
  // region R2 [56,074,240 .. 67,870,720): cst fp32 (2*16*45*8192)  OVERLAID with ab split pair
  float* cst  = ws + 56074240;
  us* ab_h    = (us*)(ws + 56074240);      // up to 4096x2880 bf16 (5,898,240 floats)
  us* ab_l    = (us*)(ws + 61972480);

  k_embed<<<(ROWS*DM+255)/256, 256, 0, stream>>>(tok, emb, h);
  for (int lyr=0; lyr<NLAYERS; ++lyr){
    // 1. split residual -> ab (in R2; prev cst dead)
    k_split_rows<<<2880, 256, 0, stream>>>(h, ab_h, ab_l, DM);
    // 2. Win -> wbuf (in R1; prev Yf dead)
    k_transcast_sp<<<dim3(ZXS/64, DM/32), 256, 0, stream>>>(Win + (size_t)lyr*DM*DPROJ, wbuf_h, wbuf_l, DM, DPROJ);
    // 3. zx = h @ Win
    k_gemm_sp<false><<<(ZXS/128)*(ROWS/128), 256, 0, stream>>>(ab_h, ab_l, wbuf_h, wbuf_l, zx, DM, ZXS, ZXS, ZXS/128);
    // 4. conv + dt
    k_conv<<<dim3((DXBC+255)/256, LL, BB), 256, 0, stream>>>(
        zx, convw + (size_t)lyr*DXBC*4, convb + (size_t)lyr*DXBC, xbc);
    k_dt<<<(ROWS*NH+255)/256, 256, 0, stream>>>(zx, dtbias + lyr*NH, dtb);
    // 5. SSD (cst overwrites ab -- dead; Yf overwrites wbuf -- dead)
    k_ssd_state_sp<<<dim3(NH, NCH, BB), 256, 0, stream>>>(xbc, dtb, Alog + lyr*NH, acs, cst);
    k_ssd_scan2<<<dim3(NH, BB, 8), 256, 0, stream>>>(acs, cst);
    k_ssd_y_sp<<<dim3(NH, NCH, BB), 256, 0, stream>>>(xbc, dtb, acs, cst, Yf);
    // 6. gate+norm -> ab (overwrites cst -- dead)
    k_gatenorm<<<ROWS, 256, 0, stream>>>(Yf, xbc, zx, Dp + lyr*NH, normw + (size_t)lyr*DI, ab_h, ab_l);
    // 7. Wout -> wbuf (overwrites Yf -- dead)
    k_transcast_sp<<<dim3(1536/64, DI/32), 256, 0, stream>>>(Wout + (size_t)lyr*DI*DM, wbuf_h, wbuf_l, DI, DM);
    // 8. h += y @ Wout   (N=1440 masked, ldc=1440)
    k_gemm_sp<true><<<(1536/128)*(ROWS/128), 256, 0, stream>>>(ab_h, ab_l, wbuf_h, wbuf_l, h, DI, DM, DM, 1536/128);
  }
  k_finalnorm<<<ROWS, 256, 0, stream>>>(h, fnw, ab_h, ab_l);
  k_split_rows<<<180, 256, 0, stream>>>(emb, wbuf_h, wbuf_l, DM);   // emb already [vocab][K]
  k_gemm_sp<false><<<(VOCABSZ/128)*(ROWS/128), 256, 0, stream>>>(ab_h, ab_l, wbuf_h, wbuf_l, (float*)d_out, DM, VOCABSZ, VOCABSZ, VOCABSZ/128);
}

// Round 6
// 27030.844 us; speedup vs baseline: 6.0852x; 1.0325x over previous
//
#include <hip/hip_runtime.h>
#include <hip/hip_bf16.h>
#include <math.h>

#define NLAYERS 32
#define DM 1440
#define DI 2880
#define DSTATE 128
#define HD 64
#define NH 45
#define VOCABSZ 256
#define CHUNK 128
#define DXBC 3136
#define DPROJ 6061
#define BB 2
#define LL 2048
#define ROWS (BB*LL)
#define NCH (LL/CHUNK)
#define ZXS 6144          // padded zx row stride
#define STR 136           // LDS leading dim for [*][128] tiles
#define STR2 68           // LDS leading dim for [*][64] tiles

typedef __attribute__((ext_vector_type(8))) short bf16x8;
typedef __attribute__((ext_vector_type(4))) float f32x4;
typedef unsigned short us;

__device__ __forceinline__ float sigmoidf_(float x){ return 1.0f/(1.0f+__expf(-x)); }
__device__ __forceinline__ us f2b(float f){
  unsigned int u = __float_as_uint(f);
  return (us)((u + 0x7FFFu + ((u>>16)&1u)) >> 16);
}
__device__ __forceinline__ float b2f(us s){
  return __uint_as_float(((unsigned int)s)<<16);
}
__device__ __forceinline__ void split2(float v, us* ph, us* pl){
  us h = f2b(v);
  *ph = h;
  *pl = f2b(v - b2f(h));
}
__device__ __forceinline__ void gl2lds16(const us* g, us* l){
  __builtin_amdgcn_global_load_lds((const __attribute__((address_space(1))) unsigned int*)g,
                                   (__attribute__((address_space(3))) unsigned int*)l, 16, 0, 0);
}
#define MFMA(a,b,c) __builtin_amdgcn_mfma_f32_16x16x32_bf16(a,b,c,0,0,0)

// ---------------- embedding lookup (h tight [4096][1440]) ----------------
__global__ void k_embed(const int* __restrict__ tok, const float* __restrict__ emb, float* __restrict__ h){
  int idx = blockIdx.x*256 + threadIdx.x;
  if (idx >= ROWS*DM) return;
  int row = idx / DM, d = idx - row*DM;
  h[idx] = emb[tok[row]*DM + d];
}

// ---------------- split fp32 rows (tight) -> hi/lo bf16 (tight) ----------------
__global__ void k_split_rows(const float* __restrict__ src, us* __restrict__ dh,
                             us* __restrict__ dl, int ncols){
  size_t e = ((size_t)blockIdx.x*256 + threadIdx.x)*8;
  const float* s = src + e;
  bf16x8 oh, ol;
  #pragma unroll
  for (int j=0;j<8;j++){
    float v = s[j];
    us hh = f2b(v);
    ((us*)&oh)[j] = hh;
    ((us*)&ol)[j] = f2b(v - b2f(hh));
  }
  *(bf16x8*)(dh + e) = oh;
  *(bf16x8*)(dl + e) = ol;
}

// ---------------- W[K][N] fp32 -> WTh/WTl[Npad][K] bf16 (zero pad rows) ----------------
__global__ void k_transcast_sp(const float* __restrict__ W, us* __restrict__ WTh,
                               us* __restrict__ WTl, int K, int N){
  __shared__ float t[32][65];
  int tid = threadIdx.x;
  int n0 = blockIdx.x*64, k0 = blockIdx.y*32;
  #pragma unroll
  for (int i=0;i<8;i++){
    int e = i*256 + tid;
    int r = e >> 6, cc = e & 63;
    int n = n0 + cc;
    t[r][cc] = (n < N) ? W[(size_t)(k0+r)*N + n] : 0.f;
  }
  __syncthreads();
  int nrow = tid >> 2, kseg = (tid & 3)*8;
  bf16x8 oh, ol;
  #pragma unroll
  for (int j=0;j<8;j++){
    float v = t[kseg+j][nrow];
    us hh = f2b(v);
    ((us*)&oh)[j] = hh;
    ((us*)&ol)[j] = f2b(v - b2f(hh));
  }
  *(bf16x8*)(WTh + (size_t)(n0+nrow)*K + k0 + kseg) = oh;
  *(bf16x8*)(WTl + (size_t)(n0+nrow)*K + k0 + kseg) = ol;
}

// ---------------- split-bf16 MFMA GEMM (R4-verified) ----------------
template<bool ACC>
__global__ __launch_bounds__(256) void k_gemm_sp(const us* __restrict__ Ah, const us* __restrict__ Al,
      const us* __restrict__ Bh, const us* __restrict__ Bl, float* __restrict__ C,
      int K, int ldc, int N, int nbx){
  __shared__ __align__(16) us sAh[4096], sAl[4096], sBh[4096], sBl[4096];
  int nwg = gridDim.x;
  int q = nwg >> 3;
  int bid = blockIdx.x;
  int wg = (bid & 7)*q + (bid >> 3);     // XCD swizzle (nwg % 8 == 0 for all our grids)
  int bx = wg % nbx, by = wg / nbx;
  int m0 = by*128, n0 = bx*128;
  int tid = threadIdx.x;
  int lane = tid & 63, wid = tid >> 6;
  int wr = wid >> 1, wc = wid & 1;
  int r4 = lane >> 2, c4 = (lane & 3)*8;
  int fr = lane & 15, fk = (lane >> 4)*8;
  f32x4 acc[4][4];
  #pragma unroll
  for (int i=0;i<4;i++)
    #pragma unroll
    for (int j=0;j<4;j++) acc[i][j] = (f32x4){0.f,0.f,0.f,0.f};
  for (int kt = 0; kt < K; kt += 32){
    __syncthreads();
    size_t ra0 = (size_t)(m0 + wid*16     + r4)*K + kt + c4;
    size_t ra1 = (size_t)(m0 + (wid+4)*16 + r4)*K + kt + c4;
    size_t rb0 = (size_t)(n0 + wid*16     + r4)*K + kt + c4;
    size_t rb1 = (size_t)(n0 + (wid+4)*16 + r4)*K + kt + c4;
    gl2lds16(Ah + ra0, sAh + wid*512);
    gl2lds16(Ah + ra1, sAh + (wid+4)*512);
    gl2lds16(Al + ra0, sAl + wid*512);
    gl2lds16(Al + ra1, sAl + (wid+4)*512);
    gl2lds16(Bh + rb0, sBh + wid*512);
    gl2lds16(Bh + rb1, sBh + (wid+4)*512);
    gl2lds16(Bl + rb0, sBl + wid*512);
    gl2lds16(Bl + rb1, sBl + (wid+4)*512);
    __syncthreads();
    bf16x8 ah[4], al[4], bh[4], bl[4];
    #pragma unroll
    for (int i=0;i<4;i++){
      int ro = (wr*64 + i*16 + fr)*32 + fk;
      int co = (wc*64 + i*16 + fr)*32 + fk;
      ah[i] = *(const bf16x8*)(sAh + ro);
      al[i] = *(const bf16x8*)(sAl + ro);
      bh[i] = *(const bf16x8*)(sBh + co);
      bl[i] = *(const bf16x8*)(sBl + co);
    }
    #pragma unroll
    for (int i=0;i<4;i++)
      #pragma unroll
      for (int j=0;j<4;j++){
        acc[i][j] = MFMA(ah[i], bh[j], acc[i][j]);
        acc[i][j] = MFMA(ah[i], bl[j], acc[i][j]);
        acc[i][j] = MFMA(al[i], bh[j], acc[i][j]);
      }
  }
  int orow = (lane>>4)*4, ocol = lane & 15;
  #pragma unroll
  for (int i=0;i<4;i++)
    #pragma unroll
    for (int j=0;j<4;j++)
      #pragma unroll
      for (int r=0;r<4;r++){
        int col = n0 + wc*64 + j*16 + ocol;
        if (col < N){
          size_t off = (size_t)(m0 + wr*64 + i*16 + orow + r)*ldc + col;
          C[off] = acc[i][j][r] + (ACC ? C[off] : 0.f);
        }
      }
}

// ---------------- causal depthwise conv(4) + SiLU -> split pair ----------------
__global__ void k_conv(const float* __restrict__ zx, const float* __restrict__ cw,
                       const float* __restrict__ cb, us* __restrict__ xbh, us* __restrict__ xbl){
  int ch = blockIdx.x*256 + threadIdx.x;
  if (ch >= DXBC) return;
  int l = blockIdx.y, b = blockIdx.z;
  int row = b*LL + l;
  float s = cb[ch];
  #pragma unroll
  for (int k=0;k<4;k++){
    int t = l - 3 + k;
    if (t >= 0) s += cw[ch*4+k] * zx[(size_t)(b*LL+t)*ZXS + DI + ch];
  }
  float v = s * sigmoidf_(s);
  split2(v, &xbh[(size_t)row*DXBC + ch], &xbl[(size_t)row*DXBC + ch]);
}

// ---------------- dt = softplus(raw + bias) ----------------
__global__ void k_dt(const float* __restrict__ zx, const float* __restrict__ dtb_in, float* __restrict__ dt){
  int idx = blockIdx.x*256+threadIdx.x;
  if (idx >= ROWS*NH) return;
  int row = idx / NH, hh = idx - row*NH;
  float v = zx[(size_t)row*ZXS + (DI+DXBC) + hh] + dtb_in[hh];
  dt[idx] = (v > 20.f) ? v : log1pf(expf(v));
}

// ---------------- SSD A: acs cumsum + chunk states; n-halved, pair staging ----------------
__global__ __launch_bounds__(256) void k_ssd_state_sp(const us* __restrict__ xbh, const us* __restrict__ xbl,
    const float* __restrict__ dtb, const float* __restrict__ Alog,
    float* __restrict__ acs, us* __restrict__ cst_h, us* __restrict__ cst_l){
  __shared__ __align__(16) us sBTh[64*STR], sBTl[64*STR];   // [n-half][l]
  __shared__ __align__(16) us sXTh[64*STR], sXTl[64*STR];   // [p][l]
  __shared__ float sAcs[128];
  __shared__ float sDt[128];
  int tid = threadIdx.x;
  int hh = blockIdx.x, c = blockIdx.y, b = blockIdx.z;
  int t0 = b*LL + c*CHUNK;
  float A_h = -__expf(Alog[hh]);
  if (tid < 128){
    float d = dtb[(size_t)(t0+tid)*NH + hh];
    sDt[tid] = d;
    sAcs[tid] = d * A_h;
  }
  __syncthreads();
  if (tid < 64){
    float v = sAcs[tid], w = sAcs[64+tid];
    #pragma unroll
    for (int off=1; off<64; off<<=1){
      float tv = __shfl_up(v, off, 64);
      float tw = __shfl_up(w, off, 64);
      if (tid >= off){ v += tv; w += tw; }
    }
    float tot = __shfl(v, 63, 64);
    sAcs[tid] = v;
    sAcs[64+tid] = w + tot;
  }
  __syncthreads();
  if (tid < 128) acs[(size_t)(t0+tid)*NH + hh] = sAcs[tid];
  float alast = sAcs[127];
  // X^T stage: scaled, needs re-split (coalesced reads along p)
  #pragma unroll 8
  for (int i=0;i<32;i++){
    int e = i*256 + tid;
    int l = e >> 6, p = e & 63;
    size_t off = (size_t)(t0+l)*DXBC + hh*HD + p;
    float v = (b2f(xbh[off]) + b2f(xbl[off])) * sDt[l] * __expf(alast - sAcs[l]);
    split2(v, &sXTh[p*STR+l], &sXTl[p*STR+l]);
  }
  int lane = tid & 63, wid = tid >> 6;
  int fr = lane & 15, fk = (lane>>4)*8;
  f32x4 acc[8];
  #pragma unroll
  for (int j=0;j<8;j++) acc[j] = (f32x4){0.f,0.f,0.f,0.f};
  #pragma unroll   // FULL unroll: nh must be compile-time (acc indexing, rule #20)
  for (int nh=0; nh<2; ++nh){
    __syncthreads();   // nh=0: covers X writes; nh=1: MFMA done reading old B-half
    #pragma unroll 8
    for (int i=0;i<32;i++){
      int e = i*256 + tid;
      int l = e >> 6, n = e & 63;                 // coalesced along n
      size_t off = (size_t)(t0+l)*DXBC + DI + nh*64 + n;
      sBTh[n*STR+l] = xbh[off];
      sBTl[n*STR+l] = xbl[off];
    }
    __syncthreads();
    #pragma unroll
    for (int ks=0; ks<4; ks++){
      bf16x8 ah = *(const bf16x8*)(sXTh + (wid*16 + fr)*STR + ks*32 + fk);
      bf16x8 al = *(const bf16x8*)(sXTl + (wid*16 + fr)*STR + ks*32 + fk);
      #pragma unroll
      for (int j=0;j<4;j++){
        bf16x8 bh = *(const bf16x8*)(sBTh + (j*16 + fr)*STR + ks*32 + fk);
        bf16x8 bl = *(const bf16x8*)(sBTl + (j*16 + fr)*STR + ks*32 + fk);
        acc[nh*4+j] = MFMA(ah, bh, acc[nh*4+j]);
        acc[nh*4+j] = MFMA(ah, bl, acc[nh*4+j]);
        acc[nh*4+j] = MFMA(al, bh, acc[nh*4+j]);
      }
    }
  }
  size_t cbase = (((size_t)(b*NCH + c)*NH) + hh)*8192;
  int orow = (lane>>4)*4;
  #pragma unroll
  for (int jj=0;jj<8;jj++)
    #pragma unroll
    for (int r=0;r<4;r++){
      int p = wid*16 + orow + r;
      int n = (jj>>2)*64 + (jj&3)*16 + fr;
      split2(acc[jj][r], &cst_h[cbase + p*128 + n], &cst_l[cbase + p*128 + n]);
    }
}

// ---------------- SSD B: sequential inter-chunk prefix (pair in place) ----------------
__global__ __launch_bounds__(256) void k_ssd_scan2(const float* __restrict__ acs,
      us* __restrict__ cst_h, us* __restrict__ cst_l){
  int tid = threadIdx.x;
  int hh = blockIdx.x, b = blockIdx.y, z = blockIdx.z;
  int base_e = z*1024;
  float P[4];
  #pragma unroll
  for (int i=0;i<4;i++) P[i] = 0.f;
  for (int c=0;c<NCH;c++){
    size_t base = (((size_t)(b*NCH + c)*NH) + hh)*8192 + base_e;
    float dec = __expf(acs[(size_t)(b*LL + c*CHUNK + CHUNK-1)*NH + hh]);
    #pragma unroll
    for (int i=0;i<4;i++){
      size_t e = base + i*256 + tid;
      float tmp = b2f(cst_h[e]) + b2f(cst_l[e]);
      split2(P[i], &cst_h[e], &cst_l[e]);
      P[i] = dec*P[i] + tmp;
    }
  }
}

// ---------------- SSD C: Y = (masked-exp-dt C@B^T)@X + exp(acs)*(C@P^T) ----------------
__global__ __launch_bounds__(256) void k_ssd_y_sp(const us* __restrict__ xbh, const us* __restrict__ xbl,
    const float* __restrict__ dtb, const float* __restrict__ acs,
    const us* __restrict__ cst_h, const us* __restrict__ cst_l, float* __restrict__ Yf){
  __shared__ __align__(16) us smem[52224];
  __shared__ float sAcs[128];
  __shared__ float sDt[128];
  // phase-1 overlay
  us* sCh = smem;          us* sCl = smem + 8704;
  us* sBh = smem + 17408;  us* sBl = smem + 26112;
  us* sPh = smem + 34816;  us* sPl = smem + 39168;
  // phase-2 overlay
  us* sSh = smem;          us* sSl = smem + 17408;
  us* sXh = smem + 34816;  us* sXl = smem + 43520;

  int tid = threadIdx.x;
  int hh = blockIdx.x, c = blockIdx.y, b = blockIdx.z;
  int t0 = b*LL + c*CHUNK;
  if (tid < 128){
    sAcs[tid] = acs[(size_t)(t0+tid)*NH + hh];
    sDt[tid]  = dtb[(size_t)(t0+tid)*NH + hh];
  }
  int lane = tid & 63, wid = tid >> 6;
  int wbase = wid*32;
  int fr = lane & 15, fk = (lane>>4)*8;
  int orow = (lane>>4)*4;
  size_t cbase = (((size_t)(b*NCH + c)*NH) + hh)*8192;

  f32x4 accS[2][8];
  f32x4 accU[2][4];
  #pragma unroll
  for (int m=0;m<2;m++){
    #pragma unroll
    for (int j=0;j<8;j++) accS[m][j] = (f32x4){0.f,0.f,0.f,0.f};
    #pragma unroll
    for (int j=0;j<4;j++) accU[m][j] = (f32x4){0.f,0.f,0.f,0.f};
  }
  #pragma unroll 1
  for (int nt=0; nt<2; ++nt){
    int nb = nt*64;
    __syncthreads();
    #pragma unroll 8
    for (int i=0;i<32;i++){
      int e = i*256 + tid;           // 8192 = 128 l x 64 nn (coalesced along nn)
      int l = e >> 6, nn = e & 63;
      size_t oc = (size_t)(t0+l)*DXBC + DI + DSTATE + nb + nn;
      size_t ob = (size_t)(t0+l)*DXBC + DI + nb + nn;
      sCh[l*STR2+nn] = xbh[oc];  sCl[l*STR2+nn] = xbl[oc];
      sBh[l*STR2+nn] = xbh[ob];  sBl[l*STR2+nn] = xbl[ob];
    }
    #pragma unroll 8
    for (int i=0;i<16;i++){
      int e = i*256 + tid;           // 4096 = 64 p x 64 nn
      int p = e >> 6, nn = e & 63;
      sPh[p*STR2+nn] = cst_h[cbase + p*128 + nb + nn];
      sPl[p*STR2+nn] = cst_l[cbase + p*128 + nb + nn];
    }
    __syncthreads();
    #pragma unroll
    for (int ks=0; ks<2; ++ks){
      int ko = ks*32 + fk;
      bf16x8 a0h = *(const bf16x8*)(sCh + (wbase+fr)*STR2 + ko);
      bf16x8 a0l = *(const bf16x8*)(sCl + (wbase+fr)*STR2 + ko);
      bf16x8 a1h = *(const bf16x8*)(sCh + (wbase+16+fr)*STR2 + ko);
      bf16x8 a1l = *(const bf16x8*)(sCl + (wbase+16+fr)*STR2 + ko);
      #pragma unroll
      for (int j=0;j<8;j++){
        bf16x8 bh = *(const bf16x8*)(sBh + (j*16+fr)*STR2 + ko);
        bf16x8 bl = *(const bf16x8*)(sBl + (j*16+fr)*STR2 + ko);
        accS[0][j] = MFMA(a0h, bh, accS[0][j]);
        accS[0][j] = MFMA(a0h, bl, accS[0][j]);
        accS[0][j] = MFMA(a0l, bh, accS[0][j]);
        accS[1][j] = MFMA(a1h, bh, accS[1][j]);
        accS[1][j] = MFMA(a1h, bl, accS[1][j]);
        accS[1][j] = MFMA(a1l, bh, accS[1][j]);
      }
      #pragma unroll
      for (int j=0;j<4;j++){
        bf16x8 ph = *(const bf16x8*)(sPh + (j*16+fr)*STR2 + ko);
        bf16x8 pl = *(const bf16x8*)(sPl + (j*16+fr)*STR2 + ko);
        accU[0][j] = MFMA(a0h, ph, accU[0][j]);
        accU[0][j] = MFMA(a0h, pl, accU[0][j]);
        accU[0][j] = MFMA(a0l, ph, accU[0][j]);
        accU[1][j] = MFMA(a1h, ph, accU[1][j]);
        accU[1][j] = MFMA(a1h, pl, accU[1][j]);
        accU[1][j] = MFMA(a1l, ph, accU[1][j]);
      }
    }
  }
  __syncthreads();
  // S -> masked exp * dt[s] -> split into LDS (overwrites C/B region)
  #pragma unroll
  for (int m=0;m<2;m++)
    #pragma unroll
    for (int j=0;j<8;j++)
      #pragma unroll
      for (int r=0;r<4;r++){
        int l = wbase + m*16 + orow + r;
        int s = j*16 + fr;
        float v = (s <= l) ? accS[m][j][r]*__expf(sAcs[l]-sAcs[s])*sDt[s] : 0.f;
        split2(v, &sSh[l*STR+s], &sSl[l*STR+s]);
      }
  // stage raw X^T [p][s] (pair copy, coalesced along p; overwrites P region + tail)
  #pragma unroll 8
  for (int i=0;i<32;i++){
    int e = i*256 + tid;             // 8192 = 128 s x 64 p
    int s = e >> 6, p = e & 63;
    size_t off = (size_t)(t0+s)*DXBC + hh*HD + p;
    sXh[p*STR + s] = xbh[off];
    sXl[p*STR + s] = xbl[off];
  }
  __syncthreads();
  f32x4 accD[2][4];
  #pragma unroll
  for (int m=0;m<2;m++)
    #pragma unroll
    for (int j=0;j<4;j++) accD[m][j] = (f32x4){0.f,0.f,0.f,0.f};
  #pragma unroll
  for (int ks=0; ks<4; ++ks){
    int ko = ks*32 + fk;
    bf16x8 a0h = *(const bf16x8*)(sSh + (wbase+fr)*STR + ko);
    bf16x8 a0l = *(const bf16x8*)(sSl + (wbase+fr)*STR + ko);
    bf16x8 a1h = *(const bf16x8*)(sSh + (wbase+16+fr)*STR + ko);
    bf16x8 a1l = *(const bf16x8*)(sSl + (wbase+16+fr)*STR + ko);
    #pragma unroll
    for (int j=0;j<4;j++){
      bf16x8 xh = *(const bf16x8*)(sXh + (j*16+fr)*STR + ko);
      bf16x8 xl = *(const bf16x8*)(sXl + (j*16+fr)*STR + ko);
      accD[0][j] = MFMA(a0h, xh, accD[0][j]);
      accD[0][j] = MFMA(a0h, xl, accD[0][j]);
      accD[0][j] = MFMA(a0l, xh, accD[0][j]);
      accD[1][j] = MFMA(a1h, xh, accD[1][j]);
      accD[1][j] = MFMA(a1h, xl, accD[1][j]);
      accD[1][j] = MFMA(a1l, xh, accD[1][j]);
    }
  }
  #pragma unroll
  for (int m=0;m<2;m++)
    #pragma unroll
    for (int r=0;r<4;r++){
      int l = wbase + m*16 + orow + r;
      float ea = __expf(sAcs[l]);
      #pragma unroll
      for (int j=0;j<4;j++)
        Yf[(size_t)(t0+l)*DI + hh*HD + j*16 + fr] = accD[m][j][r] + ea*accU[m][j][r];
    }
}

// ---------------- gate + RMSNorm -> split bf16 pair ----------------
__global__ __launch_bounds__(256) void k_gatenorm(const float* __restrict__ Yf,
                           const us* __restrict__ xbh, const us* __restrict__ xbl,
                           const float* __restrict__ zx, const float* __restrict__ Dp_l,
                           const float* __restrict__ nw, us* __restrict__ yh, us* __restrict__ yl){
  __shared__ float red[4];
  __shared__ float stot;
  int row = blockIdx.x;
  int tid = threadIdx.x;
  float yv_[12];
  float ss = 0.f;
  #pragma unroll
  for (int i=0;i<12;i++){
    int d = tid + i*256;
    if (d < DI){
      size_t xo = (size_t)row*DXBC + d;
      float xv = b2f(xbh[xo]) + b2f(xbl[xo]);
      float yv = Yf[(size_t)row*DI + d] + xv * Dp_l[d >> 6];
      float zv = zx[(size_t)row*ZXS + d];
      yv *= zv * sigmoidf_(zv);
      yv_[i] = yv;
      ss += yv*yv;
    } else yv_[i] = 0.f;
  }
  #pragma unroll
  for (int off=32; off>0; off>>=1) ss += __shfl_down(ss, off, 64);
  int lane = tid & 63, wid = tid >> 6;
  if (lane == 0) red[wid] = ss;
  __syncthreads();
  if (tid == 0) stot = red[0]+red[1]+red[2]+red[3];
  __syncthreads();
  float rs = rsqrtf(stot / (float)DI + 1e-5f);
  #pragma unroll
  for (int i=0;i<12;i++){
    int d = tid + i*256;
    if (d < DI){
      float v = yv_[i] * rs * nw[d];
      split2(v, &yh[(size_t)row*DI + d], &yl[(size_t)row*DI + d]);
    }
  }
}

// ---------------- final RMSNorm -> split bf16 pair ----------------
__global__ __launch_bounds__(256) void k_finalnorm(const float* __restrict__ h, const float* __restrict__ fnw,
                            us* __restrict__ oh, us* __restrict__ ol){
  __shared__ float red[4];
  __shared__ float stot;
  int row = blockIdx.x;
  int tid = threadIdx.x;
  float v_[6];
  float ss = 0.f;
  #pragma unroll
  for (int i=0;i<6;i++){
    int d = tid + i*256;
    if (d < DM){ v_[i] = h[(size_t)row*DM + d]; ss += v_[i]*v_[i]; }
    else v_[i] = 0.f;
  }
  #pragma unroll
  for (int off=32; off>0; off>>=1) ss += __shfl_down(ss, off, 64);
  int lane = tid & 63, wid = tid >> 6;
  if (lane == 0) red[wid] = ss;
  __syncthreads();
  if (tid == 0) stot = red[0]+red[1]+red[2]+red[3];
  __syncthreads();
  float rs = rsqrtf(stot / (float)DM + 1e-5f);
  #pragma unroll
  for (int i=0;i<6;i++){
    int d = tid + i*256;
    if (d < DM){
      float v = v_[i] * rs * fnw[d];
      split2(v, &oh[(size_t)row*DM + d], &ol[(size_t)row*DM + d]);
    }
  }
}

extern "C" void kernel_launch(void* const* d_in, const int* in_sizes, int n_in,
                              void* d_out, int out_size, void* d_ws, size_t ws_size,
                              hipStream_t stream){
  const int*   tok   = (const int*)d_in[0];
  const float* emb   = (const float*)d_in[1];
  const float* Win   = (const float*)d_in[2];
  const float* convw = (const float*)d_in[3];
  const float* convb = (const float*)d_in[4];
  const float* dtbias= (const float*)d_in[5];
  const float* Alog  = (const float*)d_in[6];
  const float* Dp    = (const float*)d_in[7];
  const float* normw = (const float*)d_in[8];
  const float* Wout  = (const float*)d_in[9];
  const float* fnw   = (const float*)d_in[10];

  float* ws = (float*)d_ws;
  // layout (floats): total 67,870,720 = 271.48 MB (identical to R4-proven)
  float* h    = ws;                        // 4096x1440 fp32
  float* zx   = ws + 5898240;              // 4096x6144 fp32
  us*    xbh  = (us*)(ws + 31064064);      // 4096x3136 bf16 hi
  us*    xbl  = (us*)(ws + 37486592);      // 4096x3136 bf16 lo
  float* dtb  = ws + 43909120;
  float* acs  = ws + 44093440;
  // region R1: Yf fp32 (4096x2880) OVERLAID with wbuf split pair
  float* Yf   = ws + 44277760;
  us* wbuf_h  = (us*)(ws + 44277760);
  us* wbuf_l  = (us*)(ws + 48701440);
  // region R2 [56,074,240 .. 67,870,720): cst pair OVERLAID with ab pair (disjoint lifetimes)
  us* cst_h   = (us*)(ws + 56074240);      // 1440*8192 us = 5,898,240 floats
  us* cst_l   = (us*)(ws + 61972480);      // FIX: +5,898,240 floats (was overlapping cst_h)
  us* ab_h    = (us*)(ws + 56074240);
  us* ab_l    = (us*)(ws + 61972480);

  k_embed<<<(ROWS*DM+255)/256, 256, 0, stream>>>(tok, emb, h);
  for (int lyr=0; lyr<NLAYERS; ++lyr){
    k_split_rows<<<2880, 256, 0, stream>>>(h, ab_h, ab_l, DM);
    k_transcast_sp<<<dim3(ZXS/64, DM/32), 256, 0, stream>>>(Win + (size_t)lyr*DM*DPROJ, wbuf_h, wbuf_l, DM, DPROJ);
    k_gemm_sp<false><<<(ZXS/128)*(ROWS/128), 256, 0, stream>>>(ab_h, ab_l, wbuf_h, wbuf_l, zx, DM, ZXS, ZXS, ZXS/128);
    k_conv<<<dim3((DXBC+255)/256, LL, BB), 256, 0, stream>>>(
        zx, convw + (size_t)lyr*DXBC*4, convb + (size_t)lyr*DXBC, xbh, xbl);
    k_dt<<<(ROWS*NH+255)/256, 256, 0, stream>>>(zx, dtbias + lyr*NH, dtb);
    k_ssd_state_sp<<<dim3(NH, NCH, BB), 256, 0, stream>>>(xbh, xbl, dtb, Alog + lyr*NH, acs, cst_h, cst_l);
    k_ssd_scan2<<<dim3(NH, BB, 8), 256, 0, stream>>>(acs, cst_h, cst_l);
    k_ssd_y_sp<<<dim3(NH, NCH, BB), 256, 0, stream>>>(xbh, xbl, dtb, acs, cst_h, cst_l, Yf);
    k_gatenorm<<<ROWS, 256, 0, stream>>>(Yf, xbh, xbl, zx, Dp + lyr*NH, normw + (size_t)lyr*DI, ab_h, ab_l);
    k_transcast_sp<<<dim3(1536/64, DI/32), 256, 0, stream>>>(Wout + (size_t)lyr*DI*DM, wbuf_h, wbuf_l, DI, DM);
    k_gemm_sp<true><<<(1536/128)*(ROWS/128), 256, 0, stream>>>(ab_h, ab_l, wbuf_h, wbuf_l, h, DI, DM, DM, 1536/128);
  }
  k_finalnorm<<<ROWS, 256, 0, stream>>>(h, fnw, ab_h, ab_l);
  k_split_rows<<<180, 256, 0, stream>>>(emb, wbuf_h, wbuf_l, DM);   // emb already [vocab][K]
  k_gemm_sp<false><<<(VOCABSZ/128)*(ROWS/128), 256, 0, stream>>>(ab_h, ab_l, wbuf_h, wbuf_l, (float*)d_out, DM, VOCABSZ, VOCABSZ, VOCABSZ/128);
}

// Round 7
// 25861.023 us; speedup vs baseline: 6.3605x; 1.0452x over previous
//
#include <hip/hip_runtime.h>
#include <hip/hip_bf16.h>
#include <math.h>

#define NLAYERS 32
#define DM 1440
#define DI 2880
#define DSTATE 128
#define HD 64
#define NH 45
#define VOCABSZ 256
#define CHUNK 128
#define DXBC 3136
#define DPROJ 6061
#define BB 2
#define LL 2048
#define ROWS (BB*LL)
#define NCH (LL/CHUNK)
#define ZXS 6144          // padded zx row stride
#define STR 136           // LDS leading dim for [*][128] tiles
#define STR2 68           // LDS leading dim for [*][64] tiles

typedef __attribute__((ext_vector_type(8))) short bf16x8;
typedef __attribute__((ext_vector_type(4))) float f32x4;
typedef unsigned short us;

__device__ __forceinline__ float sigmoidf_(float x){ return 1.0f/(1.0f+__expf(-x)); }
__device__ __forceinline__ us f2b(float f){
  unsigned int u = __float_as_uint(f);
  return (us)((u + 0x7FFFu + ((u>>16)&1u)) >> 16);
}
__device__ __forceinline__ float b2f(us s){
  return __uint_as_float(((unsigned int)s)<<16);
}
__device__ __forceinline__ void split2(float v, us* ph, us* pl){
  us h = f2b(v);
  *ph = h;
  *pl = f2b(v - b2f(h));
}
__device__ __forceinline__ void gl2lds16(const us* g, us* l){
  __builtin_amdgcn_global_load_lds((const __attribute__((address_space(1))) unsigned int*)g,
                                   (__attribute__((address_space(3))) unsigned int*)l, 16, 0, 0);
}
#define MFMA(a,b,c) __builtin_amdgcn_mfma_f32_16x16x32_bf16(a,b,c,0,0,0)

// ---------------- embedding lookup (h tight [4096][1440]) ----------------
__global__ void k_embed(const int* __restrict__ tok, const float* __restrict__ emb, float* __restrict__ h){
  int idx = blockIdx.x*256 + threadIdx.x;
  if (idx >= ROWS*DM) return;
  int row = idx / DM, d = idx - row*DM;
  h[idx] = emb[tok[row]*DM + d];
}

// ---------------- split fp32 rows (tight) -> hi/lo bf16 (tight) ----------------
__global__ void k_split_rows(const float* __restrict__ src, us* __restrict__ dh,
                             us* __restrict__ dl, int ncols){
  size_t e = ((size_t)blockIdx.x*256 + threadIdx.x)*8;
  const float* s = src + e;
  bf16x8 oh, ol;
  #pragma unroll
  for (int j=0;j<8;j++){
    float v = s[j];
    us hh = f2b(v);
    ((us*)&oh)[j] = hh;
    ((us*)&ol)[j] = f2b(v - b2f(hh));
  }
  *(bf16x8*)(dh + e) = oh;
  *(bf16x8*)(dl + e) = ol;
}

// ---------------- W[K][N] fp32 -> WTh/WTl[Npad][K] bf16 (zero pad rows) ----------------
__global__ void k_transcast_sp(const float* __restrict__ W, us* __restrict__ WTh,
                               us* __restrict__ WTl, int K, int N){
  __shared__ float t[32][65];
  int tid = threadIdx.x;
  int n0 = blockIdx.x*64, k0 = blockIdx.y*32;
  #pragma unroll
  for (int i=0;i<8;i++){
    int e = i*256 + tid;
    int r = e >> 6, cc = e & 63;
    int n = n0 + cc;
    t[r][cc] = (n < N) ? W[(size_t)(k0+r)*N + n] : 0.f;
  }
  __syncthreads();
  int nrow = tid >> 2, kseg = (tid & 3)*8;
  bf16x8 oh, ol;
  #pragma unroll
  for (int j=0;j<8;j++){
    float v = t[kseg+j][nrow];
    us hh = f2b(v);
    ((us*)&oh)[j] = hh;
    ((us*)&ol)[j] = f2b(v - b2f(hh));
  }
  *(bf16x8*)(WTh + (size_t)(n0+nrow)*K + k0 + kseg) = oh;
  *(bf16x8*)(WTl + (size_t)(n0+nrow)*K + k0 + kseg) = ol;
}

// ---------------- split-bf16 MFMA GEMM (R4-verified structure; optional split-pair epilogue) ----
template<bool ACC, bool SPL>
__global__ __launch_bounds__(256) void k_gemm_sp(const us* __restrict__ Ah, const us* __restrict__ Al,
      const us* __restrict__ Bh, const us* __restrict__ Bl, float* __restrict__ C,
      int K, int ldc, int N, int nbx, us* __restrict__ Oh, us* __restrict__ Ol){
  __shared__ __align__(16) us sAh[4096], sAl[4096], sBh[4096], sBl[4096];
  int nwg = gridDim.x;
  int q = nwg >> 3;
  int bid = blockIdx.x;
  int wg = (bid & 7)*q + (bid >> 3);     // XCD swizzle (nwg % 8 == 0 for all our grids)
  int bx = wg % nbx, by = wg / nbx;
  int m0 = by*128, n0 = bx*128;
  int tid = threadIdx.x;
  int lane = tid & 63, wid = tid >> 6;
  int wr = wid >> 1, wc = wid & 1;
  int r4 = lane >> 2, c4 = (lane & 3)*8;
  int fr = lane & 15, fk = (lane >> 4)*8;
  f32x4 acc[4][4];
  #pragma unroll
  for (int i=0;i<4;i++)
    #pragma unroll
    for (int j=0;j<4;j++) acc[i][j] = (f32x4){0.f,0.f,0.f,0.f};
  for (int kt = 0; kt < K; kt += 32){
    __syncthreads();
    size_t ra0 = (size_t)(m0 + wid*16     + r4)*K + kt + c4;
    size_t ra1 = (size_t)(m0 + (wid+4)*16 + r4)*K + kt + c4;
    size_t rb0 = (size_t)(n0 + wid*16     + r4)*K + kt + c4;
    size_t rb1 = (size_t)(n0 + (wid+4)*16 + r4)*K + kt + c4;
    gl2lds16(Ah + ra0, sAh + wid*512);
    gl2lds16(Ah + ra1, sAh + (wid+4)*512);
    gl2lds16(Al + ra0, sAl + wid*512);
    gl2lds16(Al + ra1, sAl + (wid+4)*512);
    gl2lds16(Bh + rb0, sBh + wid*512);
    gl2lds16(Bh + rb1, sBh + (wid+4)*512);
    gl2lds16(Bl + rb0, sBl + wid*512);
    gl2lds16(Bl + rb1, sBl + (wid+4)*512);
    __syncthreads();
    bf16x8 ah[4], al[4], bh[4], bl[4];
    #pragma unroll
    for (int i=0;i<4;i++){
      int ro = (wr*64 + i*16 + fr)*32 + fk;
      int co = (wc*64 + i*16 + fr)*32 + fk;
      ah[i] = *(const bf16x8*)(sAh + ro);
      al[i] = *(const bf16x8*)(sAl + ro);
      bh[i] = *(const bf16x8*)(sBh + co);
      bl[i] = *(const bf16x8*)(sBl + co);
    }
    #pragma unroll
    for (int i=0;i<4;i++)
      #pragma unroll
      for (int j=0;j<4;j++){
        acc[i][j] = MFMA(ah[i], bh[j], acc[i][j]);
        acc[i][j] = MFMA(ah[i], bl[j], acc[i][j]);
        acc[i][j] = MFMA(al[i], bh[j], acc[i][j]);
      }
  }
  int orow = (lane>>4)*4, ocol = lane & 15;
  #pragma unroll
  for (int i=0;i<4;i++)
    #pragma unroll
    for (int j=0;j<4;j++)
      #pragma unroll
      for (int r=0;r<4;r++){
        int col = n0 + wc*64 + j*16 + ocol;
        if (col < N){
          size_t off = (size_t)(m0 + wr*64 + i*16 + orow + r)*ldc + col;
          float v = acc[i][j][r] + (ACC ? C[off] : 0.f);
          C[off] = v;
          if (SPL) split2(v, &Oh[off], &Ol[off]);   // ldc==N==DM for the SPL instantiation
        }
      }
}

// ---------------- causal depthwise conv(4) + SiLU -> split pair ----------------
__global__ void k_conv(const float* __restrict__ zx, const float* __restrict__ cw,
                       const float* __restrict__ cb, us* __restrict__ xbh, us* __restrict__ xbl){
  int ch = blockIdx.x*256 + threadIdx.x;
  if (ch >= DXBC) return;
  int l = blockIdx.y, b = blockIdx.z;
  int row = b*LL + l;
  float s = cb[ch];
  #pragma unroll
  for (int k=0;k<4;k++){
    int t = l - 3 + k;
    if (t >= 0) s += cw[ch*4+k] * zx[(size_t)(b*LL+t)*ZXS + DI + ch];
  }
  float v = s * sigmoidf_(s);
  split2(v, &xbh[(size_t)row*DXBC + ch], &xbl[(size_t)row*DXBC + ch]);
}

// ---------------- dt = softplus(raw + bias) ----------------
__global__ void k_dt(const float* __restrict__ zx, const float* __restrict__ dtb_in, float* __restrict__ dt){
  int idx = blockIdx.x*256+threadIdx.x;
  if (idx >= ROWS*NH) return;
  int row = idx / NH, hh = idx - row*NH;
  float v = zx[(size_t)row*ZXS + (DI+DXBC) + hh] + dtb_in[hh];
  dt[idx] = (v > 20.f) ? v : log1pf(expf(v));
}

// ---------------- SSD A: acs cumsum + chunk states; n-halved, pair staging ----------------
__global__ __launch_bounds__(256) void k_ssd_state_sp(const us* __restrict__ xbh, const us* __restrict__ xbl,
    const float* __restrict__ dtb, const float* __restrict__ Alog,
    float* __restrict__ acs, us* __restrict__ cst_h, us* __restrict__ cst_l){
  __shared__ __align__(16) us sBTh[64*STR], sBTl[64*STR];   // [n-half][l]
  __shared__ __align__(16) us sXTh[64*STR], sXTl[64*STR];   // [p][l]
  __shared__ float sAcs[128];
  __shared__ float sDt[128];
  int tid = threadIdx.x;
  int hh = blockIdx.x, c = blockIdx.y, b = blockIdx.z;
  int t0 = b*LL + c*CHUNK;
  float A_h = -__expf(Alog[hh]);
  if (tid < 128){
    float d = dtb[(size_t)(t0+tid)*NH + hh];
    sDt[tid] = d;
    sAcs[tid] = d * A_h;
  }
  __syncthreads();
  if (tid < 64){
    float v = sAcs[tid], w = sAcs[64+tid];
    #pragma unroll
    for (int off=1; off<64; off<<=1){
      float tv = __shfl_up(v, off, 64);
      float tw = __shfl_up(w, off, 64);
      if (tid >= off){ v += tv; w += tw; }
    }
    float tot = __shfl(v, 63, 64);
    sAcs[tid] = v;
    sAcs[64+tid] = w + tot;
  }
  __syncthreads();
  if (tid < 128) acs[(size_t)(t0+tid)*NH + hh] = sAcs[tid];
  float alast = sAcs[127];
  // X^T stage: scaled, needs re-split (coalesced reads along p)
  #pragma unroll 8
  for (int i=0;i<32;i++){
    int e = i*256 + tid;
    int l = e >> 6, p = e & 63;
    size_t off = (size_t)(t0+l)*DXBC + hh*HD + p;
    float v = (b2f(xbh[off]) + b2f(xbl[off])) * sDt[l] * __expf(alast - sAcs[l]);
    split2(v, &sXTh[p*STR+l], &sXTl[p*STR+l]);
  }
  int lane = tid & 63, wid = tid >> 6;
  int fr = lane & 15, fk = (lane>>4)*8;
  f32x4 acc[8];
  #pragma unroll
  for (int j=0;j<8;j++) acc[j] = (f32x4){0.f,0.f,0.f,0.f};
  #pragma unroll   // FULL unroll: nh must be compile-time (acc indexing, rule #20)
  for (int nh=0; nh<2; ++nh){
    __syncthreads();   // nh=0: covers X writes; nh=1: MFMA done reading old B-half
    #pragma unroll 8
    for (int i=0;i<32;i++){
      int e = i*256 + tid;
      int l = e >> 6, n = e & 63;                 // coalesced along n
      size_t off = (size_t)(t0+l)*DXBC + DI + nh*64 + n;
      sBTh[n*STR+l] = xbh[off];
      sBTl[n*STR+l] = xbl[off];
    }
    __syncthreads();
    #pragma unroll
    for (int ks=0; ks<4; ks++){
      bf16x8 ah = *(const bf16x8*)(sXTh + (wid*16 + fr)*STR + ks*32 + fk);
      bf16x8 al = *(const bf16x8*)(sXTl + (wid*16 + fr)*STR + ks*32 + fk);
      #pragma unroll
      for (int j=0;j<4;j++){
        bf16x8 bh = *(const bf16x8*)(sBTh + (j*16 + fr)*STR + ks*32 + fk);
        bf16x8 bl = *(const bf16x8*)(sBTl + (j*16 + fr)*STR + ks*32 + fk);
        acc[nh*4+j] = MFMA(ah, bh, acc[nh*4+j]);
        acc[nh*4+j] = MFMA(ah, bl, acc[nh*4+j]);
        acc[nh*4+j] = MFMA(al, bh, acc[nh*4+j]);
      }
    }
  }
  size_t cbase = (((size_t)(b*NCH + c)*NH) + hh)*8192;
  int orow = (lane>>4)*4;
  #pragma unroll
  for (int jj=0;jj<8;jj++)
    #pragma unroll
    for (int r=0;r<4;r++){
      int p = wid*16 + orow + r;
      int n = (jj>>2)*64 + (jj&3)*16 + fr;
      split2(acc[jj][r], &cst_h[cbase + p*128 + n], &cst_l[cbase + p*128 + n]);
    }
}

// ---------------- SSD B: sequential inter-chunk prefix (pair in place) ----------------
__global__ __launch_bounds__(256) void k_ssd_scan2(const float* __restrict__ acs,
      us* __restrict__ cst_h, us* __restrict__ cst_l){
  int tid = threadIdx.x;
  int hh = blockIdx.x, b = blockIdx.y, z = blockIdx.z;
  int base_e = z*1024;
  float P[4];
  #pragma unroll
  for (int i=0;i<4;i++) P[i] = 0.f;
  for (int c=0;c<NCH;c++){
    size_t base = (((size_t)(b*NCH + c)*NH) + hh)*8192 + base_e;
    float dec = __expf(acs[(size_t)(b*LL + c*CHUNK + CHUNK-1)*NH + hh]);
    #pragma unroll
    for (int i=0;i<4;i++){
      size_t e = base + i*256 + tid;
      float tmp = b2f(cst_h[e]) + b2f(cst_l[e]);
      split2(P[i], &cst_h[e], &cst_l[e]);
      P[i] = dec*P[i] + tmp;
    }
  }
}

// ---------------- SSD C (512 threads, 8 waves x 16 rows): Y = (masked-exp-dt C@B^T)@X + ea*(C@P^T) ----
__global__ __launch_bounds__(512) void k_ssd_y_sp(const us* __restrict__ xbh, const us* __restrict__ xbl,
    const float* __restrict__ dtb, const float* __restrict__ acs,
    const us* __restrict__ cst_h, const us* __restrict__ cst_l, float* __restrict__ Yf){
  __shared__ __align__(16) us smem[52224];
  __shared__ float sAcs[128];
  __shared__ float sDt[128];
  // phase-1 overlay
  us* sCh = smem;          us* sCl = smem + 8704;
  us* sBh = smem + 17408;  us* sBl = smem + 26112;
  us* sPh = smem + 34816;  us* sPl = smem + 39168;
  // phase-2 overlay
  us* sSh = smem;          us* sSl = smem + 17408;
  us* sXh = smem + 34816;  us* sXl = smem + 43520;

  int tid = threadIdx.x;
  int hh = blockIdx.x, c = blockIdx.y, b = blockIdx.z;
  int t0 = b*LL + c*CHUNK;
  if (tid < 128){
    sAcs[tid] = acs[(size_t)(t0+tid)*NH + hh];
    sDt[tid]  = dtb[(size_t)(t0+tid)*NH + hh];
  }
  int lane = tid & 63, wid = tid >> 6;       // wid 0..7
  int wbase = wid*16;                        // 16 rows per wave
  int fr = lane & 15, fk = (lane>>4)*8;
  int orow = (lane>>4)*4;
  size_t cbase = (((size_t)(b*NCH + c)*NH) + hh)*8192;

  f32x4 accS[8];
  f32x4 accU[4];
  #pragma unroll
  for (int j=0;j<8;j++) accS[j] = (f32x4){0.f,0.f,0.f,0.f};
  #pragma unroll
  for (int j=0;j<4;j++) accU[j] = (f32x4){0.f,0.f,0.f,0.f};

  #pragma unroll 1
  for (int nt=0; nt<2; ++nt){
    int nb = nt*64;
    __syncthreads();
    #pragma unroll 8
    for (int i=0;i<16;i++){
      int e = i*512 + tid;           // 8192 = 128 l x 64 nn (coalesced along nn)
      int l = e >> 6, nn = e & 63;
      size_t oc = (size_t)(t0+l)*DXBC + DI + DSTATE + nb + nn;
      size_t ob = (size_t)(t0+l)*DXBC + DI + nb + nn;
      sCh[l*STR2+nn] = xbh[oc];  sCl[l*STR2+nn] = xbl[oc];
      sBh[l*STR2+nn] = xbh[ob];  sBl[l*STR2+nn] = xbl[ob];
    }
    #pragma unroll 8
    for (int i=0;i<8;i++){
      int e = i*512 + tid;           // 4096 = 64 p x 64 nn
      int p = e >> 6, nn = e & 63;
      sPh[p*STR2+nn] = cst_h[cbase + p*128 + nb + nn];
      sPl[p*STR2+nn] = cst_l[cbase + p*128 + nb + nn];
    }
    __syncthreads();
    #pragma unroll
    for (int ks=0; ks<2; ++ks){
      int ko = ks*32 + fk;
      bf16x8 a0h = *(const bf16x8*)(sCh + (wbase+fr)*STR2 + ko);
      bf16x8 a0l = *(const bf16x8*)(sCl + (wbase+fr)*STR2 + ko);
      #pragma unroll
      for (int j=0;j<8;j++){
        bf16x8 bh = *(const bf16x8*)(sBh + (j*16+fr)*STR2 + ko);
        bf16x8 bl = *(const bf16x8*)(sBl + (j*16+fr)*STR2 + ko);
        accS[j] = MFMA(a0h, bh, accS[j]);
        accS[j] = MFMA(a0h, bl, accS[j]);
        accS[j] = MFMA(a0l, bh, accS[j]);
      }
      #pragma unroll
      for (int j=0;j<4;j++){
        bf16x8 ph = *(const bf16x8*)(sPh + (j*16+fr)*STR2 + ko);
        bf16x8 pl = *(const bf16x8*)(sPl + (j*16+fr)*STR2 + ko);
        accU[j] = MFMA(a0h, ph, accU[j]);
        accU[j] = MFMA(a0h, pl, accU[j]);
        accU[j] = MFMA(a0l, ph, accU[j]);
      }
    }
  }
  __syncthreads();
  // S -> masked exp * dt[s] -> split into LDS (overwrites C/B region)
  #pragma unroll
  for (int j=0;j<8;j++)
    #pragma unroll
    for (int r=0;r<4;r++){
      int l = wbase + orow + r;
      int s = j*16 + fr;
      float v = (s <= l) ? accS[j][r]*__expf(sAcs[l]-sAcs[s])*sDt[s] : 0.f;
      split2(v, &sSh[l*STR+s], &sSl[l*STR+s]);
    }
  // stage raw X^T [p][s] (pair copy, coalesced along p; overwrites P region + tail)
  #pragma unroll 8
  for (int i=0;i<16;i++){
    int e = i*512 + tid;             // 8192 = 128 s x 64 p
    int s = e >> 6, p = e & 63;
    size_t off = (size_t)(t0+s)*DXBC + hh*HD + p;
    sXh[p*STR + s] = xbh[off];
    sXl[p*STR + s] = xbl[off];
  }
  __syncthreads();
  f32x4 accD[4];
  #pragma unroll
  for (int j=0;j<4;j++) accD[j] = (f32x4){0.f,0.f,0.f,0.f};
  #pragma unroll
  for (int ks=0; ks<4; ++ks){
    int ko = ks*32 + fk;
    bf16x8 a0h = *(const bf16x8*)(sSh + (wbase+fr)*STR + ko);
    bf16x8 a0l = *(const bf16x8*)(sSl + (wbase+fr)*STR + ko);
    #pragma unroll
    for (int j=0;j<4;j++){
      bf16x8 xh = *(const bf16x8*)(sXh + (j*16+fr)*STR + ko);
      bf16x8 xl = *(const bf16x8*)(sXl + (j*16+fr)*STR + ko);
      accD[j] = MFMA(a0h, xh, accD[j]);
      accD[j] = MFMA(a0h, xl, accD[j]);
      accD[j] = MFMA(a0l, xh, accD[j]);
    }
  }
  #pragma unroll
  for (int r=0;r<4;r++){
    int l = wbase + orow + r;
    float ea = __expf(sAcs[l]);
    #pragma unroll
    for (int j=0;j<4;j++)
      Yf[(size_t)(t0+l)*DI + hh*HD + j*16 + fr] = accD[j][r] + ea*accU[j][r];
  }
}

// ---------------- gate + RMSNorm -> split bf16 pair ----------------
__global__ __launch_bounds__(256) void k_gatenorm(const float* __restrict__ Yf,
                           const us* __restrict__ xbh, const us* __restrict__ xbl,
                           const float* __restrict__ zx, const float* __restrict__ Dp_l,
                           const float* __restrict__ nw, us* __restrict__ yh, us* __restrict__ yl){
  __shared__ float red[4];
  __shared__ float stot;
  int row = blockIdx.x;
  int tid = threadIdx.x;
  float yv_[12];
  float ss = 0.f;
  #pragma unroll
  for (int i=0;i<12;i++){
    int d = tid + i*256;
    if (d < DI){
      size_t xo = (size_t)row*DXBC + d;
      float xv = b2f(xbh[xo]) + b2f(xbl[xo]);
      float yv = Yf[(size_t)row*DI + d] + xv * Dp_l[d >> 6];
      float zv = zx[(size_t)row*ZXS + d];
      yv *= zv * sigmoidf_(zv);
      yv_[i] = yv;
      ss += yv*yv;
    } else yv_[i] = 0.f;
  }
  #pragma unroll
  for (int off=32; off>0; off>>=1) ss += __shfl_down(ss, off, 64);
  int lane = tid & 63, wid = tid >> 6;
  if (lane == 0) red[wid] = ss;
  __syncthreads();
  if (tid == 0) stot = red[0]+red[1]+red[2]+red[3];
  __syncthreads();
  float rs = rsqrtf(stot / (float)DI + 1e-5f);
  #pragma unroll
  for (int i=0;i<12;i++){
    int d = tid + i*256;
    if (d < DI){
      float v = yv_[i] * rs * nw[d];
      split2(v, &yh[(size_t)row*DI + d], &yl[(size_t)row*DI + d]);
    }
  }
}

// ---------------- final RMSNorm -> split bf16 pair ----------------
__global__ __launch_bounds__(256) void k_finalnorm(const float* __restrict__ h, const float* __restrict__ fnw,
                            us* __restrict__ oh, us* __restrict__ ol){
  __shared__ float red[4];
  __shared__ float stot;
  int row = blockIdx.x;
  int tid = threadIdx.x;
  float v_[6];
  float ss = 0.f;
  #pragma unroll
  for (int i=0;i<6;i++){
    int d = tid + i*256;
    if (d < DM){ v_[i] = h[(size_t)row*DM + d]; ss += v_[i]*v_[i]; }
    else v_[i] = 0.f;
  }
  #pragma unroll
  for (int off=32; off>0; off>>=1) ss += __shfl_down(ss, off, 64);
  int lane = tid & 63, wid = tid >> 6;
  if (lane == 0) red[wid] = ss;
  __syncthreads();
  if (tid == 0) stot = red[0]+red[1]+red[2]+red[3];
  __syncthreads();
  float rs = rsqrtf(stot / (float)DM + 1e-5f);
  #pragma unroll
  for (int i=0;i<6;i++){
    int d = tid + i*256;
    if (d < DM){
      float v = v_[i] * rs * fnw[d];
      split2(v, &oh[(size_t)row*DM + d], &ol[(size_t)row*DM + d]);
    }
  }
}

extern "C" void kernel_launch(void* const* d_in, const int* in_sizes, int n_in,
                              void* d_out, int out_size, void* d_ws, size_t ws_size,
                              hipStream_t stream){
  const int*   tok   = (const int*)d_in[0];
  const float* emb   = (const float*)d_in[1];
  const float* Win   = (const float*)d_in[2];
  const float* convw = (const float*)d_in[3];
  const float* convb = (const float*)d_in[4];
  const float* dtbias= (const float*)d_in[5];
  const float* Alog  = (const float*)d_in[6];
  const float* Dp    = (const float*)d_in[7];
  const float* normw = (const float*)d_in[8];
  const float* Wout  = (const float*)d_in[9];
  const float* fnw   = (const float*)d_in[10];

  float* ws = (float*)d_ws;
  // layout (floats): total 67,870,720 = 271.48 MB (identical to R6-proven)
  float* h    = ws;                        // 4096x1440 fp32
  float* zx   = ws + 5898240;              // 4096x6144 fp32
  us*    xbh  = (us*)(ws + 31064064);      // 4096x3136 bf16 hi
  us*    xbl  = (us*)(ws + 37486592);      // 4096x3136 bf16 lo
  // hp pair: h split [4096][1440], OVERLAID in xb region (live only GEMM2 -> next GEMM1; conv clobbers after GEMM1)
  us*    hp_h = (us*)(ws + 31064064);
  us*    hp_l = (us*)(ws + 34013184);
  float* dtb  = ws + 43909120;
  float* acs  = ws + 44093440;
  // region R1: Yf fp32 (4096x2880) OVERLAID with wbuf split pair
  float* Yf   = ws + 44277760;
  us* wbuf_h  = (us*)(ws + 44277760);
  us* wbuf_l  = (us*)(ws + 48701440);
  // region R2: cst pair OVERLAID with ab pair (disjoint lifetimes)
  us* cst_h   = (us*)(ws + 56074240);
  us* cst_l   = (us*)(ws + 61972480);
  us* ab_h    = (us*)(ws + 56074240);
  us* ab_l    = (us*)(ws + 61972480);

  k_embed<<<(ROWS*DM+255)/256, 256, 0, stream>>>(tok, emb, h);
  k_split_rows<<<2880, 256, 0, stream>>>(h, hp_h, hp_l, DM);   // initial h split
  for (int lyr=0; lyr<NLAYERS; ++lyr){
    k_transcast_sp<<<dim3(ZXS/64, DM/32), 256, 0, stream>>>(Win + (size_t)lyr*DM*DPROJ, wbuf_h, wbuf_l, DM, DPROJ);
    k_gemm_sp<false,false><<<(ZXS/128)*(ROWS/128), 256, 0, stream>>>(hp_h, hp_l, wbuf_h, wbuf_l, zx, DM, ZXS, ZXS, ZXS/128, nullptr, nullptr);
    k_conv<<<dim3((DXBC+255)/256, LL, BB), 256, 0, stream>>>(
        zx, convw + (size_t)lyr*DXBC*4, convb + (size_t)lyr*DXBC, xbh, xbl);
    k_dt<<<(ROWS*NH+255)/256, 256, 0, stream>>>(zx, dtbias + lyr*NH, dtb);
    k_ssd_state_sp<<<dim3(NH, NCH, BB), 256, 0, stream>>>(xbh, xbl, dtb, Alog + lyr*NH, acs, cst_h, cst_l);
    k_ssd_scan2<<<dim3(NH, BB, 8), 256, 0, stream>>>(acs, cst_h, cst_l);
    k_ssd_y_sp<<<dim3(NH, NCH, BB), 512, 0, stream>>>(xbh, xbl, dtb, acs, cst_h, cst_l, Yf);
    k_gatenorm<<<ROWS, 256, 0, stream>>>(Yf, xbh, xbl, zx, Dp + lyr*NH, normw + (size_t)lyr*DI, ab_h, ab_l);
    k_transcast_sp<<<dim3(1536/64, DI/32), 256, 0, stream>>>(Wout + (size_t)lyr*DI*DM, wbuf_h, wbuf_l, DI, DM);
    // h += y @ Wout; epilogue also writes hp pair for next layer's GEMM1
    k_gemm_sp<true,true><<<(1536/128)*(ROWS/128), 256, 0, stream>>>(ab_h, ab_l, wbuf_h, wbuf_l, h, DI, DM, DM, 1536/128, hp_h, hp_l);
  }
  k_finalnorm<<<ROWS, 256, 0, stream>>>(h, fnw, ab_h, ab_l);
  k_split_rows<<<180, 256, 0, stream>>>(emb, wbuf_h, wbuf_l, DM);   // emb already [vocab][K]
  k_gemm_sp<false,false><<<(VOCABSZ/128)*(ROWS/128), 256, 0, stream>>>(ab_h, ab_l, wbuf_h, wbuf_l, (float*)d_out, DM, VOCABSZ, VOCABSZ, VOCABSZ/128, nullptr, nullptr);
}

// Round 8
// 23302.444 us; speedup vs baseline: 7.0589x; 1.1098x over previous
//
#include <hip/hip_runtime.h>
#include <hip/hip_bf16.h>
#include <math.h>

#define NLAYERS 32
#define DM 1440
#define DI 2880
#define DSTATE 128
#define HD 64
#define NH 45
#define VOCABSZ 256
#define CHUNK 128
#define DXBC 3136
#define DPROJ 6061
#define BB 2
#define LL 2048
#define ROWS (BB*LL)
#define NCH (LL/CHUNK)
#define ZXS 6144          // padded zx row stride
#define STR 136           // LDS leading dim for [*][128] tiles
#define STR2 68           // LDS leading dim for [*][64] tiles

typedef __attribute__((ext_vector_type(8))) short bf16x8;
typedef __attribute__((ext_vector_type(4))) float f32x4;
typedef unsigned short us;

__device__ __forceinline__ float sigmoidf_(float x){ return 1.0f/(1.0f+__expf(-x)); }
__device__ __forceinline__ us f2b(float f){
  unsigned int u = __float_as_uint(f);
  return (us)((u + 0x7FFFu + ((u>>16)&1u)) >> 16);
}
__device__ __forceinline__ float b2f(us s){
  return __uint_as_float(((unsigned int)s)<<16);
}
__device__ __forceinline__ void split2(float v, us* ph, us* pl){
  us h = f2b(v);
  *ph = h;
  *pl = f2b(v - b2f(h));
}
__device__ __forceinline__ void gl2lds16(const us* g, us* l){
  __builtin_amdgcn_global_load_lds((const __attribute__((address_space(1))) unsigned int*)g,
                                   (__attribute__((address_space(3))) unsigned int*)l, 16, 0, 0);
}
#define MFMA(a,b,c) __builtin_amdgcn_mfma_f32_16x16x32_bf16(a,b,c,0,0,0)

// ---------------- embedding lookup (h tight [4096][1440]) ----------------
__global__ void k_embed(const int* __restrict__ tok, const float* __restrict__ emb, float* __restrict__ h){
  int idx = blockIdx.x*256 + threadIdx.x;
  if (idx >= ROWS*DM) return;
  int row = idx / DM, d = idx - row*DM;
  h[idx] = emb[tok[row]*DM + d];
}

// ---------------- split fp32 rows (tight) -> hi/lo bf16 (tight) ----------------
__global__ void k_split_rows(const float* __restrict__ src, us* __restrict__ dh,
                             us* __restrict__ dl, int ncols){
  size_t e = ((size_t)blockIdx.x*256 + threadIdx.x)*8;
  const float* s = src + e;
  bf16x8 oh, ol;
  #pragma unroll
  for (int j=0;j<8;j++){
    float v = s[j];
    us hh = f2b(v);
    ((us*)&oh)[j] = hh;
    ((us*)&ol)[j] = f2b(v - b2f(hh));
  }
  *(bf16x8*)(dh + e) = oh;
  *(bf16x8*)(dl + e) = ol;
}

// ---------------- W[K][N] fp32 -> WTh/WTl[Npad][K] bf16 (zero pad rows) ----------------
__global__ void k_transcast_sp(const float* __restrict__ W, us* __restrict__ WTh,
                               us* __restrict__ WTl, int K, int N){
  __shared__ float t[32][65];
  int tid = threadIdx.x;
  int n0 = blockIdx.x*64, k0 = blockIdx.y*32;
  #pragma unroll
  for (int i=0;i<8;i++){
    int e = i*256 + tid;
    int r = e >> 6, cc = e & 63;
    int n = n0 + cc;
    t[r][cc] = (n < N) ? W[(size_t)(k0+r)*N + n] : 0.f;
  }
  __syncthreads();
  int nrow = tid >> 2, kseg = (tid & 3)*8;
  bf16x8 oh, ol;
  #pragma unroll
  for (int j=0;j<8;j++){
    float v = t[kseg+j][nrow];
    us hh = f2b(v);
    ((us*)&oh)[j] = hh;
    ((us*)&ol)[j] = f2b(v - b2f(hh));
  }
  *(bf16x8*)(WTh + (size_t)(n0+nrow)*K + k0 + kseg) = oh;
  *(bf16x8*)(WTl + (size_t)(n0+nrow)*K + k0 + kseg) = ol;
}

// ---------------- split-bf16 MFMA GEMM (R4-verified structure; optional split-pair epilogue) ----
template<bool ACC, bool SPL>
__global__ __launch_bounds__(256) void k_gemm_sp(const us* __restrict__ Ah, const us* __restrict__ Al,
      const us* __restrict__ Bh, const us* __restrict__ Bl, float* __restrict__ C,
      int K, int ldc, int N, int nbx, us* __restrict__ Oh, us* __restrict__ Ol){
  __shared__ __align__(16) us sAh[4096], sAl[4096], sBh[4096], sBl[4096];
  int nwg = gridDim.x;
  int q = nwg >> 3;
  int bid = blockIdx.x;
  int wg = (bid & 7)*q + (bid >> 3);     // XCD swizzle (nwg % 8 == 0 for all our grids)
  int bx = wg % nbx, by = wg / nbx;
  int m0 = by*128, n0 = bx*128;
  int tid = threadIdx.x;
  int lane = tid & 63, wid = tid >> 6;
  int wr = wid >> 1, wc = wid & 1;
  int r4 = lane >> 2, c4 = (lane & 3)*8;
  int fr = lane & 15, fk = (lane >> 4)*8;
  f32x4 acc[4][4];
  #pragma unroll
  for (int i=0;i<4;i++)
    #pragma unroll
    for (int j=0;j<4;j++) acc[i][j] = (f32x4){0.f,0.f,0.f,0.f};
  for (int kt = 0; kt < K; kt += 32){
    __syncthreads();
    size_t ra0 = (size_t)(m0 + wid*16     + r4)*K + kt + c4;
    size_t ra1 = (size_t)(m0 + (wid+4)*16 + r4)*K + kt + c4;
    size_t rb0 = (size_t)(n0 + wid*16     + r4)*K + kt + c4;
    size_t rb1 = (size_t)(n0 + (wid+4)*16 + r4)*K + kt + c4;
    gl2lds16(Ah + ra0, sAh + wid*512);
    gl2lds16(Ah + ra1, sAh + (wid+4)*512);
    gl2lds16(Al + ra0, sAl + wid*512);
    gl2lds16(Al + ra1, sAl + (wid+4)*512);
    gl2lds16(Bh + rb0, sBh + wid*512);
    gl2lds16(Bh + rb1, sBh + (wid+4)*512);
    gl2lds16(Bl + rb0, sBl + wid*512);
    gl2lds16(Bl + rb1, sBl + (wid+4)*512);
    __syncthreads();
    bf16x8 ah[4], al[4], bh[4], bl[4];
    #pragma unroll
    for (int i=0;i<4;i++){
      int ro = (wr*64 + i*16 + fr)*32 + fk;
      int co = (wc*64 + i*16 + fr)*32 + fk;
      ah[i] = *(const bf16x8*)(sAh + ro);
      al[i] = *(const bf16x8*)(sAl + ro);
      bh[i] = *(const bf16x8*)(sBh + co);
      bl[i] = *(const bf16x8*)(sBl + co);
    }
    #pragma unroll
    for (int i=0;i<4;i++)
      #pragma unroll
      for (int j=0;j<4;j++){
        acc[i][j] = MFMA(ah[i], bh[j], acc[i][j]);
        acc[i][j] = MFMA(ah[i], bl[j], acc[i][j]);
        acc[i][j] = MFMA(al[i], bh[j], acc[i][j]);
      }
  }
  int orow = (lane>>4)*4, ocol = lane & 15;
  #pragma unroll
  for (int i=0;i<4;i++)
    #pragma unroll
    for (int j=0;j<4;j++)
      #pragma unroll
      for (int r=0;r<4;r++){
        int col = n0 + wc*64 + j*16 + ocol;
        if (col < N){
          size_t off = (size_t)(m0 + wr*64 + i*16 + orow + r)*ldc + col;
          float v = acc[i][j][r] + (ACC ? C[off] : 0.f);
          C[off] = v;
          if (SPL) split2(v, &Oh[off], &Ol[off]);   // ldc==N==DM for the SPL instantiation
        }
      }
}

// ---------------- causal depthwise conv(4)+SiLU, streaming along l -> split pair ----------------
__global__ __launch_bounds__(256) void k_conv2(const float* __restrict__ zx, const float* __restrict__ cw,
                        const float* __restrict__ cb, us* __restrict__ xbh, us* __restrict__ xbl){
  int ch = blockIdx.x*256 + threadIdx.x;
  if (ch >= DXBC) return;
  int l0 = blockIdx.y * 128;
  int b = blockIdx.z;
  float w0 = cw[ch*4+0], w1 = cw[ch*4+1], w2 = cw[ch*4+2], w3 = cw[ch*4+3];
  float bias = cb[ch];
  float x0=0.f, x1=0.f, x2=0.f;
  if (l0-3 >= 0) x0 = zx[(size_t)(b*LL + l0-3)*ZXS + DI + ch];
  if (l0-2 >= 0) x1 = zx[(size_t)(b*LL + l0-2)*ZXS + DI + ch];
  if (l0-1 >= 0) x2 = zx[(size_t)(b*LL + l0-1)*ZXS + DI + ch];
  for (int l = l0; l < l0+128; ++l){
    float x3 = zx[(size_t)(b*LL + l)*ZXS + DI + ch];
    float s = bias + w0*x0 + w1*x1 + w2*x2 + w3*x3;
    float v = s * sigmoidf_(s);
    size_t off = (size_t)(b*LL + l)*DXBC + ch;
    split2(v, &xbh[off], &xbl[off]);
    x0 = x1; x1 = x2; x2 = x3;
  }
}

// ---------------- dt = softplus(raw + bias) ----------------
__global__ void k_dt(const float* __restrict__ zx, const float* __restrict__ dtb_in, float* __restrict__ dt){
  int idx = blockIdx.x*256+threadIdx.x;
  if (idx >= ROWS*NH) return;
  int row = idx / NH, hh = idx - row*NH;
  float v = zx[(size_t)row*ZXS + (DI+DXBC) + hh] + dtb_in[hh];
  dt[idx] = (v > 20.f) ? v : log1pf(expf(v));
}

// ---------------- S_raw = C @ B^T per (chunk,batch) — head-independent, split-MFMA ----------------
__global__ __launch_bounds__(256) void k_sraw(const us* __restrict__ xbh, const us* __restrict__ xbl,
                                              float* __restrict__ Sraw){
  __shared__ __align__(16) us sCh[128*STR], sCl[128*STR], sB2h[128*STR], sB2l[128*STR];
  int tid = threadIdx.x;
  int c = blockIdx.x, b = blockIdx.y;
  int t0 = b*LL + c*CHUNK;
  // stage C[l][n] and B[l][n] (bf16x8 vectorized, coalesced along n)
  #pragma unroll
  for (int i=0;i<8;i++){
    int e = i*256 + tid;          // 2048 vec8 elems = 128 l x 16 seg
    int l = e >> 4, seg = (e & 15)*8;
    size_t oc = (size_t)(t0+l)*DXBC + DI + DSTATE + seg;
    size_t ob = (size_t)(t0+l)*DXBC + DI + seg;
    *(bf16x8*)(sCh + l*STR + seg) = *(const bf16x8*)(xbh + oc);
    *(bf16x8*)(sCl + l*STR + seg) = *(const bf16x8*)(xbl + oc);
    *(bf16x8*)(sB2h + l*STR + seg) = *(const bf16x8*)(xbh + ob);
    *(bf16x8*)(sB2l + l*STR + seg) = *(const bf16x8*)(xbl + ob);
  }
  __syncthreads();
  int lane = tid & 63, wid = tid >> 6;
  int wbase = wid*32;
  int fr = lane & 15, fk = (lane>>4)*8;
  int orow = (lane>>4)*4;
  f32x4 accS[2][8];
  #pragma unroll
  for (int m=0;m<2;m++)
    #pragma unroll
    for (int j=0;j<8;j++) accS[m][j] = (f32x4){0.f,0.f,0.f,0.f};
  #pragma unroll
  for (int ks=0; ks<4; ++ks){
    int ko = ks*32 + fk;
    bf16x8 a0h = *(const bf16x8*)(sCh + (wbase+fr)*STR + ko);
    bf16x8 a0l = *(const bf16x8*)(sCl + (wbase+fr)*STR + ko);
    bf16x8 a1h = *(const bf16x8*)(sCh + (wbase+16+fr)*STR + ko);
    bf16x8 a1l = *(const bf16x8*)(sCl + (wbase+16+fr)*STR + ko);
    #pragma unroll
    for (int j=0;j<8;j++){
      bf16x8 bh = *(const bf16x8*)(sB2h + (j*16+fr)*STR + ko);
      bf16x8 bl = *(const bf16x8*)(sB2l + (j*16+fr)*STR + ko);
      accS[0][j] = MFMA(a0h, bh, accS[0][j]);
      accS[0][j] = MFMA(a0h, bl, accS[0][j]);
      accS[0][j] = MFMA(a0l, bh, accS[0][j]);
      accS[1][j] = MFMA(a1h, bh, accS[1][j]);
      accS[1][j] = MFMA(a1h, bl, accS[1][j]);
      accS[1][j] = MFMA(a1l, bh, accS[1][j]);
    }
  }
  size_t sbase = ((size_t)(b*NCH + c))*16384;
  #pragma unroll
  for (int m=0;m<2;m++)
    #pragma unroll
    for (int j=0;j<8;j++)
      #pragma unroll
      for (int r=0;r<4;r++){
        int l = wbase + m*16 + orow + r;
        int s = j*16 + fr;
        Sraw[sbase + l*128 + s] = accS[m][j][r];
      }
}

// ---------------- SSD A: acs cumsum + chunk states; n-halved, pair staging (R6-verified) --------
__global__ __launch_bounds__(256) void k_ssd_state_sp(const us* __restrict__ xbh, const us* __restrict__ xbl,
    const float* __restrict__ dtb, const float* __restrict__ Alog,
    float* __restrict__ acs, us* __restrict__ cst_h, us* __restrict__ cst_l){
  __shared__ __align__(16) us sBTh[64*STR], sBTl[64*STR];   // [n-half][l]
  __shared__ __align__(16) us sXTh[64*STR], sXTl[64*STR];   // [p][l]
  __shared__ float sAcs[128];
  __shared__ float sDt[128];
  int tid = threadIdx.x;
  int hh = blockIdx.x, c = blockIdx.y, b = blockIdx.z;
  int t0 = b*LL + c*CHUNK;
  float A_h = -__expf(Alog[hh]);
  if (tid < 128){
    float d = dtb[(size_t)(t0+tid)*NH + hh];
    sDt[tid] = d;
    sAcs[tid] = d * A_h;
  }
  __syncthreads();
  if (tid < 64){
    float v = sAcs[tid], w = sAcs[64+tid];
    #pragma unroll
    for (int off=1; off<64; off<<=1){
      float tv = __shfl_up(v, off, 64);
      float tw = __shfl_up(w, off, 64);
      if (tid >= off){ v += tv; w += tw; }
    }
    float tot = __shfl(v, 63, 64);
    sAcs[tid] = v;
    sAcs[64+tid] = w + tot;
  }
  __syncthreads();
  if (tid < 128) acs[(size_t)(t0+tid)*NH + hh] = sAcs[tid];
  float alast = sAcs[127];
  // X^T stage: scaled, needs re-split (coalesced reads along p)
  #pragma unroll 8
  for (int i=0;i<32;i++){
    int e = i*256 + tid;
    int l = e >> 6, p = e & 63;
    size_t off = (size_t)(t0+l)*DXBC + hh*HD + p;
    float v = (b2f(xbh[off]) + b2f(xbl[off])) * sDt[l] * __expf(alast - sAcs[l]);
    split2(v, &sXTh[p*STR+l], &sXTl[p*STR+l]);
  }
  int lane = tid & 63, wid = tid >> 6;
  int fr = lane & 15, fk = (lane>>4)*8;
  f32x4 acc[8];
  #pragma unroll
  for (int j=0;j<8;j++) acc[j] = (f32x4){0.f,0.f,0.f,0.f};
  #pragma unroll   // FULL unroll: nh must be compile-time (acc indexing, rule #20)
  for (int nh=0; nh<2; ++nh){
    __syncthreads();   // nh=0: covers X writes; nh=1: MFMA done reading old B-half
    #pragma unroll 8
    for (int i=0;i<32;i++){
      int e = i*256 + tid;
      int l = e >> 6, n = e & 63;                 // coalesced along n
      size_t off = (size_t)(t0+l)*DXBC + DI + nh*64 + n;
      sBTh[n*STR+l] = xbh[off];
      sBTl[n*STR+l] = xbl[off];
    }
    __syncthreads();
    #pragma unroll
    for (int ks=0; ks<4; ks++){
      bf16x8 ah = *(const bf16x8*)(sXTh + (wid*16 + fr)*STR + ks*32 + fk);
      bf16x8 al = *(const bf16x8*)(sXTl + (wid*16 + fr)*STR + ks*32 + fk);
      #pragma unroll
      for (int j=0;j<4;j++){
        bf16x8 bh = *(const bf16x8*)(sBTh + (j*16 + fr)*STR + ks*32 + fk);
        bf16x8 bl = *(const bf16x8*)(sBTl + (j*16 + fr)*STR + ks*32 + fk);
        acc[nh*4+j] = MFMA(ah, bh, acc[nh*4+j]);
        acc[nh*4+j] = MFMA(ah, bl, acc[nh*4+j]);
        acc[nh*4+j] = MFMA(al, bh, acc[nh*4+j]);
      }
    }
  }
  size_t cbase = (((size_t)(b*NCH + c)*NH) + hh)*8192;
  int orow = (lane>>4)*4;
  #pragma unroll
  for (int jj=0;jj<8;jj++)
    #pragma unroll
    for (int r=0;r<4;r++){
      int p = wid*16 + orow + r;
      int n = (jj>>2)*64 + (jj&3)*16 + fr;
      split2(acc[jj][r], &cst_h[cbase + p*128 + n], &cst_l[cbase + p*128 + n]);
    }
}

// ---------------- SSD B: sequential inter-chunk prefix (pair in place) ----------------
__global__ __launch_bounds__(256) void k_ssd_scan2(const float* __restrict__ acs,
      us* __restrict__ cst_h, us* __restrict__ cst_l){
  int tid = threadIdx.x;
  int hh = blockIdx.x, b = blockIdx.y, z = blockIdx.z;
  int base_e = z*1024;
  float P[4];
  #pragma unroll
  for (int i=0;i<4;i++) P[i] = 0.f;
  for (int c=0;c<NCH;c++){
    size_t base = (((size_t)(b*NCH + c)*NH) + hh)*8192 + base_e;
    float dec = __expf(acs[(size_t)(b*LL + c*CHUNK + CHUNK-1)*NH + hh]);
    #pragma unroll
    for (int i=0;i<4;i++){
      size_t e = base + i*256 + tid;
      float tmp = b2f(cst_h[e]) + b2f(cst_l[e]);
      split2(P[i], &cst_h[e], &cst_l[e]);
      P[i] = dec*P[i] + tmp;
    }
  }
}

// ---------------- SSD C (512 threads, half-K phases, 53KB LDS) ----------------
// Y = (masked exp(acs_l-acs_s)*dt_s * Sraw) @ X + exp(acs)*(C @ P^T)
__global__ __launch_bounds__(512) void k_ssd_y_sp(const us* __restrict__ xbh, const us* __restrict__ xbl,
    const float* __restrict__ dtb, const float* __restrict__ acs,
    const us* __restrict__ cst_h, const us* __restrict__ cst_l,
    const float* __restrict__ Sraw, float* __restrict__ Yf){
  __shared__ __align__(16) us smem[26112];
  __shared__ float sAcs[128];
  __shared__ float sDt[128];
  // phase-1 overlay: C-half pair + P-half pair
  us* sCh = smem;          us* sCl = smem + 8704;
  us* sPh = smem + 17408;  us* sPl = smem + 21760;
  // phase-2 overlay: S-half pair + X-half pair
  us* sSh = smem;          us* sSl = smem + 8704;
  us* sXh = smem + 17408;  us* sXl = smem + 21760;

  int tid = threadIdx.x;
  int hh = blockIdx.x, c = blockIdx.y, b = blockIdx.z;
  int t0 = b*LL + c*CHUNK;
  if (tid < 128){
    sAcs[tid] = acs[(size_t)(t0+tid)*NH + hh];
    sDt[tid]  = dtb[(size_t)(t0+tid)*NH + hh];
  }
  int lane = tid & 63, wid = tid >> 6;       // wid 0..7
  int wbase = wid*16;                        // 16 rows per wave
  int fr = lane & 15, fk = (lane>>4)*8;
  int orow = (lane>>4)*4;
  size_t cbase = (((size_t)(b*NCH + c)*NH) + hh)*8192;
  size_t sbase = ((size_t)(b*NCH + c))*16384;

  f32x4 accU[4], accD[4];
  #pragma unroll
  for (int j=0;j<4;j++){
    accU[j] = (f32x4){0.f,0.f,0.f,0.f};
    accD[j] = (f32x4){0.f,0.f,0.f,0.f};
  }

  // ---- phase 1: U = C @ P^T over two n-halves ----
  #pragma unroll
  for (int nt=0; nt<2; ++nt){
    int nb = nt*64;
    __syncthreads();
    #pragma unroll 8
    for (int i=0;i<16;i++){
      int e = i*512 + tid;           // 8192 = 128 l x 64 nn (coalesced along nn)
      int l = e >> 6, nn = e & 63;
      size_t oc = (size_t)(t0+l)*DXBC + DI + DSTATE + nb + nn;
      sCh[l*STR2+nn] = xbh[oc];  sCl[l*STR2+nn] = xbl[oc];
    }
    #pragma unroll 8
    for (int i=0;i<8;i++){
      int e = i*512 + tid;           // 4096 = 64 p x 64 nn
      int p = e >> 6, nn = e & 63;
      sPh[p*STR2+nn] = cst_h[cbase + p*128 + nb + nn];
      sPl[p*STR2+nn] = cst_l[cbase + p*128 + nb + nn];
    }
    __syncthreads();
    #pragma unroll
    for (int ks=0; ks<2; ++ks){
      int ko = ks*32 + fk;
      bf16x8 a0h = *(const bf16x8*)(sCh + (wbase+fr)*STR2 + ko);
      bf16x8 a0l = *(const bf16x8*)(sCl + (wbase+fr)*STR2 + ko);
      #pragma unroll
      for (int j=0;j<4;j++){
        bf16x8 ph = *(const bf16x8*)(sPh + (j*16+fr)*STR2 + ko);
        bf16x8 pl = *(const bf16x8*)(sPl + (j*16+fr)*STR2 + ko);
        accU[j] = MFMA(a0h, ph, accU[j]);
        accU[j] = MFMA(a0h, pl, accU[j]);
        accU[j] = MFMA(a0l, ph, accU[j]);
      }
    }
  }

  // ---- phase 2: D = S @ X over two s-halves; S from Sraw with mask*exp*dt ----
  #pragma unroll
  for (int sh=0; sh<2; ++sh){
    __syncthreads();
    #pragma unroll 8
    for (int i=0;i<16;i++){
      int e = i*512 + tid;           // 8192 = 128 l x 64 ss (coalesced fp32 reads along ss)
      int l = e >> 6, ss = e & 63;
      int s = sh*64 + ss;
      float raw = Sraw[sbase + l*128 + s];
      float v = (s <= l) ? raw*__expf(sAcs[l]-sAcs[s])*sDt[s] : 0.f;
      split2(v, &sSh[l*STR2+ss], &sSl[l*STR2+ss]);
    }
    #pragma unroll 8
    for (int i=0;i<8;i++){
      int e = i*512 + tid;           // 4096 = 64 sl x 64 p (coalesced along p)
      int sl = e >> 6, p = e & 63;
      size_t off = (size_t)(t0 + sh*64 + sl)*DXBC + hh*HD + p;
      sXh[p*STR2 + sl] = xbh[off];
      sXl[p*STR2 + sl] = xbl[off];
    }
    __syncthreads();
    #pragma unroll
    for (int ks=0; ks<2; ++ks){
      int ko = ks*32 + fk;
      bf16x8 a0h = *(const bf16x8*)(sSh + (wbase+fr)*STR2 + ko);
      bf16x8 a0l = *(const bf16x8*)(sSl + (wbase+fr)*STR2 + ko);
      #pragma unroll
      for (int j=0;j<4;j++){
        bf16x8 xh = *(const bf16x8*)(sXh + (j*16+fr)*STR2 + ko);
        bf16x8 xl = *(const bf16x8*)(sXl + (j*16+fr)*STR2 + ko);
        accD[j] = MFMA(a0h, xh, accD[j]);
        accD[j] = MFMA(a0h, xl, accD[j]);
        accD[j] = MFMA(a0l, xh, accD[j]);
      }
    }
  }
  #pragma unroll
  for (int r=0;r<4;r++){
    int l = wbase + orow + r;
    float ea = __expf(sAcs[l]);
    #pragma unroll
    for (int j=0;j<4;j++)
      Yf[(size_t)(t0+l)*DI + hh*HD + j*16 + fr] = accD[j][r] + ea*accU[j][r];
  }
}

// ---------------- gate + RMSNorm -> split bf16 pair ----------------
__global__ __launch_bounds__(256) void k_gatenorm(const float* __restrict__ Yf,
                           const us* __restrict__ xbh, const us* __restrict__ xbl,
                           const float* __restrict__ zx, const float* __restrict__ Dp_l,
                           const float* __restrict__ nw, us* __restrict__ yh, us* __restrict__ yl){
  __shared__ float red[4];
  __shared__ float stot;
  int row = blockIdx.x;
  int tid = threadIdx.x;
  float yv_[12];
  float ss = 0.f;
  #pragma unroll
  for (int i=0;i<12;i++){
    int d = tid + i*256;
    if (d < DI){
      size_t xo = (size_t)row*DXBC + d;
      float xv = b2f(xbh[xo]) + b2f(xbl[xo]);
      float yv = Yf[(size_t)row*DI + d] + xv * Dp_l[d >> 6];
      float zv = zx[(size_t)row*ZXS + d];
      yv *= zv * sigmoidf_(zv);
      yv_[i] = yv;
      ss += yv*yv;
    } else yv_[i] = 0.f;
  }
  #pragma unroll
  for (int off=32; off>0; off>>=1) ss += __shfl_down(ss, off, 64);
  int lane = tid & 63, wid = tid >> 6;
  if (lane == 0) red[wid] = ss;
  __syncthreads();
  if (tid == 0) stot = red[0]+red[1]+red[2]+red[3];
  __syncthreads();
  float rs = rsqrtf(stot / (float)DI + 1e-5f);
  #pragma unroll
  for (int i=0;i<12;i++){
    int d = tid + i*256;
    if (d < DI){
      float v = yv_[i] * rs * nw[d];
      split2(v, &yh[(size_t)row*DI + d], &yl[(size_t)row*DI + d]);
    }
  }
}

// ---------------- final RMSNorm -> split bf16 pair ----------------
__global__ __launch_bounds__(256) void k_finalnorm(const float* __restrict__ h, const float* __restrict__ fnw,
                            us* __restrict__ oh, us* __restrict__ ol){
  __shared__ float red[4];
  __shared__ float stot;
  int row = blockIdx.x;
  int tid = threadIdx.x;
  float v_[6];
  float ss = 0.f;
  #pragma unroll
  for (int i=0;i<6;i++){
    int d = tid + i*256;
    if (d < DM){ v_[i] = h[(size_t)row*DM + d]; ss += v_[i]*v_[i]; }
    else v_[i] = 0.f;
  }
  #pragma unroll
  for (int off=32; off>0; off>>=1) ss += __shfl_down(ss, off, 64);
  int lane = tid & 63, wid = tid >> 6;
  if (lane == 0) red[wid] = ss;
  __syncthreads();
  if (tid == 0) stot = red[0]+red[1]+red[2]+red[3];
  __syncthreads();
  float rs = rsqrtf(stot / (float)DM + 1e-5f);
  #pragma unroll
  for (int i=0;i<6;i++){
    int d = tid + i*256;
    if (d < DM){
      float v = v_[i] * rs * fnw[d];
      split2(v, &oh[(size_t)row*DM + d], &ol[(size_t)row*DM + d]);
    }
  }
}

extern "C" void kernel_launch(void* const* d_in, const int* in_sizes, int n_in,
                              void* d_out, int out_size, void* d_ws, size_t ws_size,
                              hipStream_t stream){
  const int*   tok   = (const int*)d_in[0];
  const float* emb   = (const float*)d_in[1];
  const float* Win   = (const float*)d_in[2];
  const float* convw = (const float*)d_in[3];
  const float* convb = (const float*)d_in[4];
  const float* dtbias= (const float*)d_in[5];
  const float* Alog  = (const float*)d_in[6];
  const float* Dp    = (const float*)d_in[7];
  const float* normw = (const float*)d_in[8];
  const float* Wout  = (const float*)d_in[9];
  const float* fnw   = (const float*)d_in[10];

  float* ws = (float*)d_ws;
  // layout (floats): 273.58 MB total (ws poison fill shows 4.36 GB available)
  float* h    = ws;                        // 4096x1440 fp32
  float* zx   = ws + 5898240;              // 4096x6144 fp32
  us*    xbh  = (us*)(ws + 31064064);      // 4096x3136 bf16 hi
  us*    xbl  = (us*)(ws + 37486592);      // 4096x3136 bf16 lo
  // hp pair: h split, OVERLAID in xb region (live GEMM2 -> next GEMM1; conv clobbers after GEMM1)
  us*    hp_h = (us*)(ws + 31064064);
  us*    hp_l = (us*)(ws + 34013184);
  float* dtb  = ws + 43909120;
  float* acs  = ws + 44093440;
  // region R1: Yf fp32 (4096x2880) OVERLAID with wbuf split pair
  float* Yf   = ws + 44277760;
  us* wbuf_h  = (us*)(ws + 44277760);
  us* wbuf_l  = (us*)(ws + 48701440);
  // region R2: cst pair OVERLAID with ab pair (disjoint lifetimes)
  us* cst_h   = (us*)(ws + 56074240);
  us* cst_l   = (us*)(ws + 61972480);
  us* ab_h    = (us*)(ws + 56074240);
  us* ab_l    = (us*)(ws + 61972480);
  float* Sraw = ws + 67870720;             // 32 x 128 x 128 fp32 = 524,288 floats

  k_embed<<<(ROWS*DM+255)/256, 256, 0, stream>>>(tok, emb, h);
  k_split_rows<<<2880, 256, 0, stream>>>(h, hp_h, hp_l, DM);   // initial h split
  for (int lyr=0; lyr<NLAYERS; ++lyr){
    k_transcast_sp<<<dim3(ZXS/64, DM/32), 256, 0, stream>>>(Win + (size_t)lyr*DM*DPROJ, wbuf_h, wbuf_l, DM, DPROJ);
    k_gemm_sp<false,false><<<(ZXS/128)*(ROWS/128), 256, 0, stream>>>(hp_h, hp_l, wbuf_h, wbuf_l, zx, DM, ZXS, ZXS, ZXS/128, nullptr, nullptr);
    k_conv2<<<dim3(13, 16, BB), 256, 0, stream>>>(
        zx, convw + (size_t)lyr*DXBC*4, convb + (size_t)lyr*DXBC, xbh, xbl);
    k_dt<<<(ROWS*NH+255)/256, 256, 0, stream>>>(zx, dtbias + lyr*NH, dtb);
    k_sraw<<<dim3(NCH, BB), 256, 0, stream>>>(xbh, xbl, Sraw);
    k_ssd_state_sp<<<dim3(NH, NCH, BB), 256, 0, stream>>>(xbh, xbl, dtb, Alog + lyr*NH, acs, cst_h, cst_l);
    k_ssd_scan2<<<dim3(NH, BB, 8), 256, 0, stream>>>(acs, cst_h, cst_l);
    k_ssd_y_sp<<<dim3(NH, NCH, BB), 512, 0, stream>>>(xbh, xbl, dtb, acs, cst_h, cst_l, Sraw, Yf);
    k_gatenorm<<<ROWS, 256, 0, stream>>>(Yf, xbh, xbl, zx, Dp + lyr*NH, normw + (size_t)lyr*DI, ab_h, ab_l);
    k_transcast_sp<<<dim3(1536/64, DI/32), 256, 0, stream>>>(Wout + (size_t)lyr*DI*DM, wbuf_h, wbuf_l, DI, DM);
    // h += y @ Wout; epilogue also writes hp pair for next layer's GEMM1
    k_gemm_sp<true,true><<<(1536/128)*(ROWS/128), 256, 0, stream>>>(ab_h, ab_l, wbuf_h, wbuf_l, h, DI, DM, DM, 1536/128, hp_h, hp_l);
  }
  k_finalnorm<<<ROWS, 256, 0, stream>>>(h, fnw, ab_h, ab_l);
  k_split_rows<<<180, 256, 0, stream>>>(emb, wbuf_h, wbuf_l, DM);   // emb already [vocab][K]
  k_gemm_sp<false,false><<<(VOCABSZ/128)*(ROWS/128), 256, 0, stream>>>(ab_h, ab_l, wbuf_h, wbuf_l, (float*)d_out, DM, VOCABSZ, VOCABSZ, VOCABSZ/128, nullptr, nullptr);
}

// Round 9
// 22796.812 us; speedup vs baseline: 7.2154x; 1.0222x over previous
//
#include <hip/hip_runtime.h>
#include <hip/hip_bf16.h>
#include <math.h>

#define NLAYERS 32
#define DM 1440
#define DI 2880
#define DSTATE 128
#define HD 64
#define NH 45
#define VOCABSZ 256
#define CHUNK 128
#define DXBC 3136
#define DPROJ 6061
#define BB 2
#define LL 2048
#define ROWS (BB*LL)
#define NCH (LL/CHUNK)
#define ZXS 6144          // padded zx row stride
#define STR 136           // LDS leading dim for [*][128] tiles
#define STR2 68           // LDS leading dim for [*][64] tiles

typedef __attribute__((ext_vector_type(8))) short bf16x8;
typedef __attribute__((ext_vector_type(4))) float f32x4;
typedef unsigned short us;

__device__ __forceinline__ float sigmoidf_(float x){ return 1.0f/(1.0f+__expf(-x)); }
__device__ __forceinline__ us f2b(float f){
  unsigned int u = __float_as_uint(f);
  return (us)((u + 0x7FFFu + ((u>>16)&1u)) >> 16);
}
__device__ __forceinline__ float b2f(us s){
  return __uint_as_float(((unsigned int)s)<<16);
}
__device__ __forceinline__ void split2(float v, us* ph, us* pl){
  us h = f2b(v);
  *ph = h;
  *pl = f2b(v - b2f(h));
}
__device__ __forceinline__ void gl2lds16(const us* g, us* l){
  __builtin_amdgcn_global_load_lds((const __attribute__((address_space(1))) unsigned int*)g,
                                   (__attribute__((address_space(3))) unsigned int*)l, 16, 0, 0);
}
#define MFMA(a,b,c) __builtin_amdgcn_mfma_f32_16x16x32_bf16(a,b,c,0,0,0)

// ---------------- embedding lookup (h tight [4096][1440]) ----------------
__global__ void k_embed(const int* __restrict__ tok, const float* __restrict__ emb, float* __restrict__ h){
  int idx = blockIdx.x*256 + threadIdx.x;
  if (idx >= ROWS*DM) return;
  int row = idx / DM, d = idx - row*DM;
  h[idx] = emb[tok[row]*DM + d];
}

// ---------------- split fp32 rows (tight) -> hi/lo bf16 (tight) ----------------
__global__ void k_split_rows(const float* __restrict__ src, us* __restrict__ dh,
                             us* __restrict__ dl, int ncols){
  size_t e = ((size_t)blockIdx.x*256 + threadIdx.x)*8;
  const float* s = src + e;
  bf16x8 oh, ol;
  #pragma unroll
  for (int j=0;j<8;j++){
    float v = s[j];
    us hh = f2b(v);
    ((us*)&oh)[j] = hh;
    ((us*)&ol)[j] = f2b(v - b2f(hh));
  }
  *(bf16x8*)(dh + e) = oh;
  *(bf16x8*)(dl + e) = ol;
}

// ---------------- W[K][N] fp32 -> WTh/WTl[Npad][K] bf16 (zero pad rows) ----------------
__global__ void k_transcast_sp(const float* __restrict__ W, us* __restrict__ WTh,
                               us* __restrict__ WTl, int K, int N){
  __shared__ float t[32][65];
  int tid = threadIdx.x;
  int n0 = blockIdx.x*64, k0 = blockIdx.y*32;
  #pragma unroll
  for (int i=0;i<8;i++){
    int e = i*256 + tid;
    int r = e >> 6, cc = e & 63;
    int n = n0 + cc;
    t[r][cc] = (n < N) ? W[(size_t)(k0+r)*N + n] : 0.f;
  }
  __syncthreads();
  int nrow = tid >> 2, kseg = (tid & 3)*8;
  bf16x8 oh, ol;
  #pragma unroll
  for (int j=0;j<8;j++){
    float v = t[kseg+j][nrow];
    us hh = f2b(v);
    ((us*)&oh)[j] = hh;
    ((us*)&ol)[j] = f2b(v - b2f(hh));
  }
  *(bf16x8*)(WTh + (size_t)(n0+nrow)*K + k0 + kseg) = oh;
  *(bf16x8*)(WTl + (size_t)(n0+nrow)*K + k0 + kseg) = ol;
}

// ---------------- split-bf16 MFMA GEMM (R4-verified core; 2D-clustered XCD swizzle) ----------
// Swizzle: (bid&7)->XCD chunk, then within-XCD 4 by-rows share each bx sweep so the
// B (weight) panel is read ONCE per XCD while 4 A panels stay L2-resident.
// Requires nwg % 8 == 0 and (nwg/8) % (4*... ) handled by: nwg = nbx*nby, nby % 4 == 0.
template<bool ACC, bool SPL>
__global__ __launch_bounds__(256) void k_gemm_sp(const us* __restrict__ Ah, const us* __restrict__ Al,
      const us* __restrict__ Bh, const us* __restrict__ Bl, float* __restrict__ C,
      int K, int ldc, int N, int nbx, us* __restrict__ Oh, us* __restrict__ Ol){
  __shared__ __align__(16) us sAh[4096], sAl[4096], sBh[4096], sBl[4096];
  int nwg = gridDim.x;
  int q = nwg >> 3;
  int bid = blockIdx.x;
  int wg = (bid & 7)*q + (bid >> 3);     // XCD-contiguous chunk
  int grp = wg / (4*nbx);
  int rem = wg - grp*4*nbx;
  int by = grp*4 + (rem & 3);            // 4 by-rows interleaved within each bx sweep
  int bx = rem >> 2;
  int m0 = by*128, n0 = bx*128;
  int tid = threadIdx.x;
  int lane = tid & 63, wid = tid >> 6;
  int wr = wid >> 1, wc = wid & 1;
  int r4 = lane >> 2, c4 = (lane & 3)*8;
  int fr = lane & 15, fk = (lane >> 4)*8;
  f32x4 acc[4][4];
  #pragma unroll
  for (int i=0;i<4;i++)
    #pragma unroll
    for (int j=0;j<4;j++) acc[i][j] = (f32x4){0.f,0.f,0.f,0.f};
  for (int kt = 0; kt < K; kt += 32){
    __syncthreads();
    size_t ra0 = (size_t)(m0 + wid*16     + r4)*K + kt + c4;
    size_t ra1 = (size_t)(m0 + (wid+4)*16 + r4)*K + kt + c4;
    size_t rb0 = (size_t)(n0 + wid*16     + r4)*K + kt + c4;
    size_t rb1 = (size_t)(n0 + (wid+4)*16 + r4)*K + kt + c4;
    gl2lds16(Ah + ra0, sAh + wid*512);
    gl2lds16(Ah + ra1, sAh + (wid+4)*512);
    gl2lds16(Al + ra0, sAl + wid*512);
    gl2lds16(Al + ra1, sAl + (wid+4)*512);
    gl2lds16(Bh + rb0, sBh + wid*512);
    gl2lds16(Bh + rb1, sBh + (wid+4)*512);
    gl2lds16(Bl + rb0, sBl + wid*512);
    gl2lds16(Bl + rb1, sBl + (wid+4)*512);
    __syncthreads();
    bf16x8 ah[4], al[4], bh[4], bl[4];
    #pragma unroll
    for (int i=0;i<4;i++){
      int ro = (wr*64 + i*16 + fr)*32 + fk;
      int co = (wc*64 + i*16 + fr)*32 + fk;
      ah[i] = *(const bf16x8*)(sAh + ro);
      al[i] = *(const bf16x8*)(sAl + ro);
      bh[i] = *(const bf16x8*)(sBh + co);
      bl[i] = *(const bf16x8*)(sBl + co);
    }
    #pragma unroll
    for (int i=0;i<4;i++)
      #pragma unroll
      for (int j=0;j<4;j++){
        acc[i][j] = MFMA(ah[i], bh[j], acc[i][j]);
        acc[i][j] = MFMA(ah[i], bl[j], acc[i][j]);
        acc[i][j] = MFMA(al[i], bh[j], acc[i][j]);
      }
  }
  int orow = (lane>>4)*4, ocol = lane & 15;
  #pragma unroll
  for (int i=0;i<4;i++)
    #pragma unroll
    for (int j=0;j<4;j++)
      #pragma unroll
      for (int r=0;r<4;r++){
        int col = n0 + wc*64 + j*16 + ocol;
        if (col < N){
          size_t off = (size_t)(m0 + wr*64 + i*16 + orow + r)*ldc + col;
          float v = acc[i][j][r] + (ACC ? C[off] : 0.f);
          C[off] = v;
          if (SPL) split2(v, &Oh[off], &Ol[off]);   // ldc==N==DM for the SPL instantiation
        }
      }
}

// ---------------- causal depthwise conv(4)+SiLU, streaming along l -> split pair ----------------
__global__ __launch_bounds__(256) void k_conv2(const float* __restrict__ zx, const float* __restrict__ cw,
                        const float* __restrict__ cb, us* __restrict__ xbh, us* __restrict__ xbl){
  int ch = blockIdx.x*256 + threadIdx.x;
  if (ch >= DXBC) return;
  int l0 = blockIdx.y * 128;
  int b = blockIdx.z;
  float w0 = cw[ch*4+0], w1 = cw[ch*4+1], w2 = cw[ch*4+2], w3 = cw[ch*4+3];
  float bias = cb[ch];
  float x0=0.f, x1=0.f, x2=0.f;
  if (l0-3 >= 0) x0 = zx[(size_t)(b*LL + l0-3)*ZXS + DI + ch];
  if (l0-2 >= 0) x1 = zx[(size_t)(b*LL + l0-2)*ZXS + DI + ch];
  if (l0-1 >= 0) x2 = zx[(size_t)(b*LL + l0-1)*ZXS + DI + ch];
  for (int l = l0; l < l0+128; ++l){
    float x3 = zx[(size_t)(b*LL + l)*ZXS + DI + ch];
    float s = bias + w0*x0 + w1*x1 + w2*x2 + w3*x3;
    float v = s * sigmoidf_(s);
    size_t off = (size_t)(b*LL + l)*DXBC + ch;
    split2(v, &xbh[off], &xbl[off]);
    x0 = x1; x1 = x2; x2 = x3;
  }
}

// ---------------- dt = softplus(raw + bias) ----------------
__global__ void k_dt(const float* __restrict__ zx, const float* __restrict__ dtb_in, float* __restrict__ dt){
  int idx = blockIdx.x*256+threadIdx.x;
  if (idx >= ROWS*NH) return;
  int row = idx / NH, hh = idx - row*NH;
  float v = zx[(size_t)row*ZXS + (DI+DXBC) + hh] + dtb_in[hh];
  dt[idx] = (v > 20.f) ? v : log1pf(expf(v));
}

// ---------------- S_raw = C @ B^T per (chunk,batch) — head-independent, split-MFMA ----------------
__global__ __launch_bounds__(256) void k_sraw(const us* __restrict__ xbh, const us* __restrict__ xbl,
                                              float* __restrict__ Sraw){
  __shared__ __align__(16) us sCh[128*STR], sCl[128*STR], sB2h[128*STR], sB2l[128*STR];
  int tid = threadIdx.x;
  int c = blockIdx.x, b = blockIdx.y;
  int t0 = b*LL + c*CHUNK;
  // stage C[l][n] and B[l][n] (bf16x8 vectorized, coalesced along n)
  #pragma unroll
  for (int i=0;i<8;i++){
    int e = i*256 + tid;          // 2048 vec8 elems = 128 l x 16 seg
    int l = e >> 4, seg = (e & 15)*8;
    size_t oc = (size_t)(t0+l)*DXBC + DI + DSTATE + seg;
    size_t ob = (size_t)(t0+l)*DXBC + DI + seg;
    *(bf16x8*)(sCh + l*STR + seg) = *(const bf16x8*)(xbh + oc);
    *(bf16x8*)(sCl + l*STR + seg) = *(const bf16x8*)(xbl + oc);
    *(bf16x8*)(sB2h + l*STR + seg) = *(const bf16x8*)(xbh + ob);
    *(bf16x8*)(sB2l + l*STR + seg) = *(const bf16x8*)(xbl + ob);
  }
  __syncthreads();
  int lane = tid & 63, wid = tid >> 6;
  int wbase = wid*32;
  int fr = lane & 15, fk = (lane>>4)*8;
  int orow = (lane>>4)*4;
  f32x4 accS[2][8];
  #pragma unroll
  for (int m=0;m<2;m++)
    #pragma unroll
    for (int j=0;j<8;j++) accS[m][j] = (f32x4){0.f,0.f,0.f,0.f};
  #pragma unroll
  for (int ks=0; ks<4; ++ks){
    int ko = ks*32 + fk;
    bf16x8 a0h = *(const bf16x8*)(sCh + (wbase+fr)*STR + ko);
    bf16x8 a0l = *(const bf16x8*)(sCl + (wbase+fr)*STR + ko);
    bf16x8 a1h = *(const bf16x8*)(sCh + (wbase+16+fr)*STR + ko);
    bf16x8 a1l = *(const bf16x8*)(sCl + (wbase+16+fr)*STR + ko);
    #pragma unroll
    for (int j=0;j<8;j++){
      bf16x8 bh = *(const bf16x8*)(sB2h + (j*16+fr)*STR + ko);
      bf16x8 bl = *(const bf16x8*)(sB2l + (j*16+fr)*STR + ko);
      accS[0][j] = MFMA(a0h, bh, accS[0][j]);
      accS[0][j] = MFMA(a0h, bl, accS[0][j]);
      accS[0][j] = MFMA(a0l, bh, accS[0][j]);
      accS[1][j] = MFMA(a1h, bh, accS[1][j]);
      accS[1][j] = MFMA(a1h, bl, accS[1][j]);
      accS[1][j] = MFMA(a1l, bh, accS[1][j]);
    }
  }
  size_t sbase = ((size_t)(b*NCH + c))*16384;
  #pragma unroll
  for (int m=0;m<2;m++)
    #pragma unroll
    for (int j=0;j<8;j++)
      #pragma unroll
      for (int r=0;r<4;r++){
        int l = wbase + m*16 + orow + r;
        int s = j*16 + fr;
        Sraw[sbase + l*128 + s] = accS[m][j][r];
      }
}

// ---------------- SSD A: acs cumsum + chunk states; n-halved, pair staging (R6-verified) --------
__global__ __launch_bounds__(256) void k_ssd_state_sp(const us* __restrict__ xbh, const us* __restrict__ xbl,
    const float* __restrict__ dtb, const float* __restrict__ Alog,
    float* __restrict__ acs, us* __restrict__ cst_h, us* __restrict__ cst_l){
  __shared__ __align__(16) us sBTh[64*STR], sBTl[64*STR];   // [n-half][l]
  __shared__ __align__(16) us sXTh[64*STR], sXTl[64*STR];   // [p][l]
  __shared__ float sAcs[128];
  __shared__ float sDt[128];
  int tid = threadIdx.x;
  int hh = blockIdx.x, c = blockIdx.y, b = blockIdx.z;
  int t0 = b*LL + c*CHUNK;
  float A_h = -__expf(Alog[hh]);
  if (tid < 128){
    float d = dtb[(size_t)(t0+tid)*NH + hh];
    sDt[tid] = d;
    sAcs[tid] = d * A_h;
  }
  __syncthreads();
  if (tid < 64){
    float v = sAcs[tid], w = sAcs[64+tid];
    #pragma unroll
    for (int off=1; off<64; off<<=1){
      float tv = __shfl_up(v, off, 64);
      float tw = __shfl_up(w, off, 64);
      if (tid >= off){ v += tv; w += tw; }
    }
    float tot = __shfl(v, 63, 64);
    sAcs[tid] = v;
    sAcs[64+tid] = w + tot;
  }
  __syncthreads();
  if (tid < 128) acs[(size_t)(t0+tid)*NH + hh] = sAcs[tid];
  float alast = sAcs[127];
  // X^T stage: scaled, needs re-split (coalesced reads along p)
  #pragma unroll 8
  for (int i=0;i<32;i++){
    int e = i*256 + tid;
    int l = e >> 6, p = e & 63;
    size_t off = (size_t)(t0+l)*DXBC + hh*HD + p;
    float v = (b2f(xbh[off]) + b2f(xbl[off])) * sDt[l] * __expf(alast - sAcs[l]);
    split2(v, &sXTh[p*STR+l], &sXTl[p*STR+l]);
  }
  int lane = tid & 63, wid = tid >> 6;
  int fr = lane & 15, fk = (lane>>4)*8;
  f32x4 acc[8];
  #pragma unroll
  for (int j=0;j<8;j++) acc[j] = (f32x4){0.f,0.f,0.f,0.f};
  #pragma unroll   // FULL unroll: nh must be compile-time (acc indexing, rule #20)
  for (int nh=0; nh<2; ++nh){
    __syncthreads();   // nh=0: covers X writes; nh=1: MFMA done reading old B-half
    #pragma unroll 8
    for (int i=0;i<32;i++){
      int e = i*256 + tid;
      int l = e >> 6, n = e & 63;                 // coalesced along n
      size_t off = (size_t)(t0+l)*DXBC + DI + nh*64 + n;
      sBTh[n*STR+l] = xbh[off];
      sBTl[n*STR+l] = xbl[off];
    }
    __syncthreads();
    #pragma unroll
    for (int ks=0; ks<4; ks++){
      bf16x8 ah = *(const bf16x8*)(sXTh + (wid*16 + fr)*STR + ks*32 + fk);
      bf16x8 al = *(const bf16x8*)(sXTl + (wid*16 + fr)*STR + ks*32 + fk);
      #pragma unroll
      for (int j=0;j<4;j++){
        bf16x8 bh = *(const bf16x8*)(sBTh + (j*16 + fr)*STR + ks*32 + fk);
        bf16x8 bl = *(const bf16x8*)(sBTl + (j*16 + fr)*STR + ks*32 + fk);
        acc[nh*4+j] = MFMA(ah, bh, acc[nh*4+j]);
        acc[nh*4+j] = MFMA(ah, bl, acc[nh*4+j]);
        acc[nh*4+j] = MFMA(al, bh, acc[nh*4+j]);
      }
    }
  }
  size_t cbase = (((size_t)(b*NCH + c)*NH) + hh)*8192;
  int orow = (lane>>4)*4;
  #pragma unroll
  for (int jj=0;jj<8;jj++)
    #pragma unroll
    for (int r=0;r<4;r++){
      int p = wid*16 + orow + r;
      int n = (jj>>2)*64 + (jj&3)*16 + fr;
      split2(acc[jj][r], &cst_h[cbase + p*128 + n], &cst_l[cbase + p*128 + n]);
    }
}

// ---------------- SSD B: sequential inter-chunk prefix (pair in place) ----------------
__global__ __launch_bounds__(256) void k_ssd_scan2(const float* __restrict__ acs,
      us* __restrict__ cst_h, us* __restrict__ cst_l){
  int tid = threadIdx.x;
  int hh = blockIdx.x, b = blockIdx.y, z = blockIdx.z;
  int base_e = z*1024;
  float P[4];
  #pragma unroll
  for (int i=0;i<4;i++) P[i] = 0.f;
  for (int c=0;c<NCH;c++){
    size_t base = (((size_t)(b*NCH + c)*NH) + hh)*8192 + base_e;
    float dec = __expf(acs[(size_t)(b*LL + c*CHUNK + CHUNK-1)*NH + hh]);
    #pragma unroll
    for (int i=0;i<4;i++){
      size_t e = base + i*256 + tid;
      float tmp = b2f(cst_h[e]) + b2f(cst_l[e]);
      split2(P[i], &cst_h[e], &cst_l[e]);
      P[i] = dec*P[i] + tmp;
    }
  }
}

// ---------------- SSD C (512 threads, half-K phases, 53KB LDS) ----------------
// Y = (masked exp(acs_l-acs_s)*dt_s * Sraw) @ X + exp(acs)*(C @ P^T)
__global__ __launch_bounds__(512) void k_ssd_y_sp(const us* __restrict__ xbh, const us* __restrict__ xbl,
    const float* __restrict__ dtb, const float* __restrict__ acs,
    const us* __restrict__ cst_h, const us* __restrict__ cst_l,
    const float* __restrict__ Sraw, float* __restrict__ Yf){
  __shared__ __align__(16) us smem[26112];
  __shared__ float sAcs[128];
  __shared__ float sDt[128];
  // phase-1 overlay: C-half pair + P-half pair
  us* sCh = smem;          us* sCl = smem + 8704;
  us* sPh = smem + 17408;  us* sPl = smem + 21760;
  // phase-2 overlay: S-half pair + X-half pair
  us* sSh = smem;          us* sSl = smem + 8704;
  us* sXh = smem + 17408;  us* sXl = smem + 21760;

  int tid = threadIdx.x;
  int hh = blockIdx.x, c = blockIdx.y, b = blockIdx.z;
  int t0 = b*LL + c*CHUNK;
  if (tid < 128){
    sAcs[tid] = acs[(size_t)(t0+tid)*NH + hh];
    sDt[tid]  = dtb[(size_t)(t0+tid)*NH + hh];
  }
  int lane = tid & 63, wid = tid >> 6;       // wid 0..7
  int wbase = wid*16;                        // 16 rows per wave
  int fr = lane & 15, fk = (lane>>4)*8;
  int orow = (lane>>4)*4;
  size_t cbase = (((size_t)(b*NCH + c)*NH) + hh)*8192;
  size_t sbase = ((size_t)(b*NCH + c))*16384;

  f32x4 accU[4], accD[4];
  #pragma unroll
  for (int j=0;j<4;j++){
    accU[j] = (f32x4){0.f,0.f,0.f,0.f};
    accD[j] = (f32x4){0.f,0.f,0.f,0.f};
  }

  // ---- phase 1: U = C @ P^T over two n-halves ----
  #pragma unroll
  for (int nt=0; nt<2; ++nt){
    int nb = nt*64;
    __syncthreads();
    #pragma unroll 8
    for (int i=0;i<16;i++){
      int e = i*512 + tid;           // 8192 = 128 l x 64 nn (coalesced along nn)
      int l = e >> 6, nn = e & 63;
      size_t oc = (size_t)(t0+l)*DXBC + DI + DSTATE + nb + nn;
      sCh[l*STR2+nn] = xbh[oc];  sCl[l*STR2+nn] = xbl[oc];
    }
    #pragma unroll 8
    for (int i=0;i<8;i++){
      int e = i*512 + tid;           // 4096 = 64 p x 64 nn
      int p = e >> 6, nn = e & 63;
      sPh[p*STR2+nn] = cst_h[cbase + p*128 + nb + nn];
      sPl[p*STR2+nn] = cst_l[cbase + p*128 + nb + nn];
    }
    __syncthreads();
    #pragma unroll
    for (int ks=0; ks<2; ++ks){
      int ko = ks*32 + fk;
      bf16x8 a0h = *(const bf16x8*)(sCh + (wbase+fr)*STR2 + ko);
      bf16x8 a0l = *(const bf16x8*)(sCl + (wbase+fr)*STR2 + ko);
      #pragma unroll
      for (int j=0;j<4;j++){
        bf16x8 ph = *(const bf16x8*)(sPh + (j*16+fr)*STR2 + ko);
        bf16x8 pl = *(const bf16x8*)(sPl + (j*16+fr)*STR2 + ko);
        accU[j] = MFMA(a0h, ph, accU[j]);
        accU[j] = MFMA(a0h, pl, accU[j]);
        accU[j] = MFMA(a0l, ph, accU[j]);
      }
    }
  }

  // ---- phase 2: D = S @ X over two s-halves; S from Sraw with mask*exp*dt ----
  #pragma unroll
  for (int sh=0; sh<2; ++sh){
    __syncthreads();
    #pragma unroll 8
    for (int i=0;i<16;i++){
      int e = i*512 + tid;           // 8192 = 128 l x 64 ss (coalesced fp32 reads along ss)
      int l = e >> 6, ss = e & 63;
      int s = sh*64 + ss;
      float raw = Sraw[sbase + l*128 + s];
      float v = (s <= l) ? raw*__expf(sAcs[l]-sAcs[s])*sDt[s] : 0.f;
      split2(v, &sSh[l*STR2+ss], &sSl[l*STR2+ss]);
    }
    #pragma unroll 8
    for (int i=0;i<8;i++){
      int e = i*512 + tid;           // 4096 = 64 sl x 64 p (coalesced along p)
      int sl = e >> 6, p = e & 63;
      size_t off = (size_t)(t0 + sh*64 + sl)*DXBC + hh*HD + p;
      sXh[p*STR2 + sl] = xbh[off];
      sXl[p*STR2 + sl] = xbl[off];
    }
    __syncthreads();
    #pragma unroll
    for (int ks=0; ks<2; ++ks){
      int ko = ks*32 + fk;
      bf16x8 a0h = *(const bf16x8*)(sSh + (wbase+fr)*STR2 + ko);
      bf16x8 a0l = *(const bf16x8*)(sSl + (wbase+fr)*STR2 + ko);
      #pragma unroll
      for (int j=0;j<4;j++){
        bf16x8 xh = *(const bf16x8*)(sXh + (j*16+fr)*STR2 + ko);
        bf16x8 xl = *(const bf16x8*)(sXl + (j*16+fr)*STR2 + ko);
        accD[j] = MFMA(a0h, xh, accD[j]);
        accD[j] = MFMA(a0h, xl, accD[j]);
        accD[j] = MFMA(a0l, xh, accD[j]);
      }
    }
  }
  #pragma unroll
  for (int r=0;r<4;r++){
    int l = wbase + orow + r;
    float ea = __expf(sAcs[l]);
    #pragma unroll
    for (int j=0;j<4;j++)
      Yf[(size_t)(t0+l)*DI + hh*HD + j*16 + fr] = accD[j][r] + ea*accU[j][r];
  }
}

// ---------------- gate + RMSNorm -> split bf16 pair ----------------
__global__ __launch_bounds__(256) void k_gatenorm(const float* __restrict__ Yf,
                           const us* __restrict__ xbh, const us* __restrict__ xbl,
                           const float* __restrict__ zx, const float* __restrict__ Dp_l,
                           const float* __restrict__ nw, us* __restrict__ yh, us* __restrict__ yl){
  __shared__ float red[4];
  __shared__ float stot;
  int row = blockIdx.x;
  int tid = threadIdx.x;
  float yv_[12];
  float ss = 0.f;
  #pragma unroll
  for (int i=0;i<12;i++){
    int d = tid + i*256;
    if (d < DI){
      size_t xo = (size_t)row*DXBC + d;
      float xv = b2f(xbh[xo]) + b2f(xbl[xo]);
      float yv = Yf[(size_t)row*DI + d] + xv * Dp_l[d >> 6];
      float zv = zx[(size_t)row*ZXS + d];
      yv *= zv * sigmoidf_(zv);
      yv_[i] = yv;
      ss += yv*yv;
    } else yv_[i] = 0.f;
  }
  #pragma unroll
  for (int off=32; off>0; off>>=1) ss += __shfl_down(ss, off, 64);
  int lane = tid & 63, wid = tid >> 6;
  if (lane == 0) red[wid] = ss;
  __syncthreads();
  if (tid == 0) stot = red[0]+red[1]+red[2]+red[3];
  __syncthreads();
  float rs = rsqrtf(stot / (float)DI + 1e-5f);
  #pragma unroll
  for (int i=0;i<12;i++){
    int d = tid + i*256;
    if (d < DI){
      float v = yv_[i] * rs * nw[d];
      split2(v, &yh[(size_t)row*DI + d], &yl[(size_t)row*DI + d]);
    }
  }
}

// ---------------- final RMSNorm -> split bf16 pair ----------------
__global__ __launch_bounds__(256) void k_finalnorm(const float* __restrict__ h, const float* __restrict__ fnw,
                            us* __restrict__ oh, us* __restrict__ ol){
  __shared__ float red[4];
  __shared__ float stot;
  int row = blockIdx.x;
  int tid = threadIdx.x;
  float v_[6];
  float ss = 0.f;
  #pragma unroll
  for (int i=0;i<6;i++){
    int d = tid + i*256;
    if (d < DM){ v_[i] = h[(size_t)row*DM + d]; ss += v_[i]*v_[i]; }
    else v_[i] = 0.f;
  }
  #pragma unroll
  for (int off=32; off>0; off>>=1) ss += __shfl_down(ss, off, 64);
  int lane = tid & 63, wid = tid >> 6;
  if (lane == 0) red[wid] = ss;
  __syncthreads();
  if (tid == 0) stot = red[0]+red[1]+red[2]+red[3];
  __syncthreads();
  float rs = rsqrtf(stot / (float)DM + 1e-5f);
  #pragma unroll
  for (int i=0;i<6;i++){
    int d = tid + i*256;
    if (d < DM){
      float v = v_[i] * rs * fnw[d];
      split2(v, &oh[(size_t)row*DM + d], &ol[(size_t)row*DM + d]);
    }
  }
}

extern "C" void kernel_launch(void* const* d_in, const int* in_sizes, int n_in,
                              void* d_out, int out_size, void* d_ws, size_t ws_size,
                              hipStream_t stream){
  const int*   tok   = (const int*)d_in[0];
  const float* emb   = (const float*)d_in[1];
  const float* Win   = (const float*)d_in[2];
  const float* convw = (const float*)d_in[3];
  const float* convb = (const float*)d_in[4];
  const float* dtbias= (const float*)d_in[5];
  const float* Alog  = (const float*)d_in[6];
  const float* Dp    = (const float*)d_in[7];
  const float* normw = (const float*)d_in[8];
  const float* Wout  = (const float*)d_in[9];
  const float* fnw   = (const float*)d_in[10];

  float* ws = (float*)d_ws;
  // layout (floats): 273.58 MB total
  float* h    = ws;                        // 4096x1440 fp32
  float* zx   = ws + 5898240;              // 4096x6144 fp32
  us*    xbh  = (us*)(ws + 31064064);      // 4096x3136 bf16 hi
  us*    xbl  = (us*)(ws + 37486592);      // 4096x3136 bf16 lo
  // hp pair: h split, OVERLAID in xb region (live GEMM2 -> next GEMM1; conv clobbers after GEMM1)
  us*    hp_h = (us*)(ws + 31064064);
  us*    hp_l = (us*)(ws + 34013184);
  float* dtb  = ws + 43909120;
  float* acs  = ws + 44093440;
  // region R1: Yf fp32 (4096x2880) OVERLAID with wbuf split pair
  float* Yf   = ws + 44277760;
  us* wbuf_h  = (us*)(ws + 44277760);
  us* wbuf_l  = (us*)(ws + 48701440);
  // region R2: cst pair OVERLAID with ab pair (disjoint lifetimes)
  us* cst_h   = (us*)(ws + 56074240);
  us* cst_l   = (us*)(ws + 61972480);
  us* ab_h    = (us*)(ws + 56074240);
  us* ab_l    = (us*)(ws + 61972480);
  float* Sraw = ws + 67870720;             // 32 x 128 x 128 fp32 = 524,288 floats

  k_embed<<<(ROWS*DM+255)/256, 256, 0, stream>>>(tok, emb, h);
  k_split_rows<<<2880, 256, 0, stream>>>(h, hp_h, hp_l, DM);   // initial h split
  for (int lyr=0; lyr<NLAYERS; ++lyr){
    k_transcast_sp<<<dim3(ZXS/64, DM/32), 256, 0, stream>>>(Win + (size_t)lyr*DM*DPROJ, wbuf_h, wbuf_l, DM, DPROJ);
    k_gemm_sp<false,false><<<(ZXS/128)*(ROWS/128), 256, 0, stream>>>(hp_h, hp_l, wbuf_h, wbuf_l, zx, DM, ZXS, ZXS, ZXS/128, nullptr, nullptr);
    k_conv2<<<dim3(13, 16, BB), 256, 0, stream>>>(
        zx, convw + (size_t)lyr*DXBC*4, convb + (size_t)lyr*DXBC, xbh, xbl);
    k_dt<<<(ROWS*NH+255)/256, 256, 0, stream>>>(zx, dtbias + lyr*NH, dtb);
    k_sraw<<<dim3(NCH, BB), 256, 0, stream>>>(xbh, xbl, Sraw);
    k_ssd_state_sp<<<dim3(NH, NCH, BB), 256, 0, stream>>>(xbh, xbl, dtb, Alog + lyr*NH, acs, cst_h, cst_l);
    k_ssd_scan2<<<dim3(NH, BB, 8), 256, 0, stream>>>(acs, cst_h, cst_l);
    k_ssd_y_sp<<<dim3(NH, NCH, BB), 512, 0, stream>>>(xbh, xbl, dtb, acs, cst_h, cst_l, Sraw, Yf);
    k_gatenorm<<<ROWS, 256, 0, stream>>>(Yf, xbh, xbl, zx, Dp + lyr*NH, normw + (size_t)lyr*DI, ab_h, ab_l);
    k_transcast_sp<<<dim3(1536/64, DI/32), 256, 0, stream>>>(Wout + (size_t)lyr*DI*DM, wbuf_h, wbuf_l, DI, DM);
    // h += y @ Wout; epilogue also writes hp pair for next layer's GEMM1
    k_gemm_sp<true,true><<<(1536/128)*(ROWS/128), 256, 0, stream>>>(ab_h, ab_l, wbuf_h, wbuf_l, h, DI, DM, DM, 1536/128, hp_h, hp_l);
  }
  k_finalnorm<<<ROWS, 256, 0, stream>>>(h, fnw, ab_h, ab_l);
  k_split_rows<<<180, 256, 0, stream>>>(emb, wbuf_h, wbuf_l, DM);   // emb already [vocab][K]
  k_gemm_sp<false,false><<<(VOCABSZ/128)*(ROWS/128), 256, 0, stream>>>(ab_h, ab_l, wbuf_h, wbuf_l, (float*)d_out, DM, VOCABSZ, VOCABSZ, VOCABSZ/128, nullptr, nullptr);
}